// Round 5
// baseline (1197.868 us; speedup 1.0000x reference)
//
#include <hip/hip_runtime.h>
#include <hip/hip_bf16.h>
#include <math.h>

// Problem constants (from reference)
#define BGRAPH 8192
#define NPG 32
#define EPG 64
#define NNODE (BGRAPH * NPG)   // 262144
#define NEDGE (BGRAPH * EPG)   // 524288
#define CELLD 908
#define BN_EPS 1e-5f

typedef __attribute__((ext_vector_type(8))) short bf16x8;   // 8 bf16 = 4 VGPRs
typedef __attribute__((ext_vector_type(4))) float f32x4;
typedef __attribute__((ext_vector_type(4))) unsigned short us4;

__device__ __forceinline__ unsigned short f2bf(float f)
{
    unsigned int u = __float_as_uint(f);
    u = (u + 0x7FFFu + ((u >> 16) & 1u)) >> 16;   // RNE
    return (unsigned short)u;
}

// in_mode: 0=raw, 1=relu((x-m)*iv), 2=elu((x-m)*iv), 3=(relu(x)-m)*iv
__device__ __forceinline__ float apply_in(float v, int mode, float mn, float iv)
{
    if (mode == 1)      { v = (v - mn) * iv; v = fmaxf(v, 0.f); }
    else if (mode == 2) { v = (v - mn) * iv; v = (v > 0.f) ? v : expm1f(v); }
    else if (mode == 3) { v = fmaxf(v, 0.f); v = (v - mn) * iv; }
    return v;
}

__global__ void zero_buf(float* __restrict__ p, int n)
{
    int i = blockIdx.x * blockDim.x + threadIdx.x;
    if (i < n) p[i] = 0.f;
}

// ---------------------------------------------------------------------------
// Fused weight transpose+convert: wt[n*K+k] = bf16(w[k*N+n]) for 11 layers.
// ---------------------------------------------------------------------------
struct TSeg { const float* w; unsigned short* wt; int K; int N; int off; };
struct TArgs { TSeg s[11]; int total; };

__global__ void transpose_w(TArgs a)
{
    int i = blockIdx.x * blockDim.x + threadIdx.x;
    if (i >= a.total) return;
    int j = 0;
    while (j < 10 && i >= a.s[j + 1].off) ++j;
    int idx = i - a.s[j].off;
    int K = a.s[j].K, N = a.s[j].N;
    int n = idx / K, k = idx - n * K;
    a.s[j].wt[idx] = f2bf(a.s[j].w[(size_t)k * N + n]);
}

// ---------------------------------------------------------------------------
// Register-A MFMA GEMM. Tile 128 x NT, K <= KSTEPS*32 (K in {9,128,256}),
// N == NT. W resident in LDS once (no K-loop). A loaded directly to regs,
// BN transform fused on load. Optional: dual A source (f1 concat), skip C,
// column stats of u / relu(u), per-graph max-pool of relu(u) (wave==graph).
// In-place safe (A may == C: all A reads precede epilogue writes, block reads
// only its own 128 rows). M must be a multiple of 128.
// ---------------------------------------------------------------------------
template<int KSTEPS, int NT>
__launch_bounds__(256)
__global__ void gemm_rA(const float* __restrict__ A, const float* __restrict__ A2,
                        int lda, int K, int stats_K, int ksplit,
                        const unsigned short* __restrict__ Wt,
                        const float* __restrict__ bias, float* __restrict__ C,
                        const float* __restrict__ in_stats, float inv_sM, int in_mode,
                        float* __restrict__ out_stats, int stats_mode, int out_act,
                        float* __restrict__ pool_out)
{
    constexpr int LSTRW = KSTEPS * 32 + 8;   // LDS row stride (ushorts)
    constexpr int NSUB = NT / 16;
    __shared__ unsigned short Ws_l[NT * LSTRW];
    __shared__ float pm[KSTEPS * 32], pv[KSTEPS * 32];
    __shared__ float red[4][2][NT];

    int tid  = threadIdx.x;
    int wave = tid >> 6;
    int lane = tid & 63;
    int quad = lane >> 4;
    int l16  = lane & 15;
    int m0   = blockIdx.x * 128;

    // ---- stage W (full K) and BN params ----
    const bool kvec = ((K & 3) == 0);
    for (int i = tid; i < NT * (KSTEPS * 8); i += 256) {
        int n = i / (KSTEPS * 8), g4 = i % (KSTEPS * 8);
        int k = g4 * 4;
        us4 w = (us4){0, 0, 0, 0};
        if (k < K) {
            const unsigned short* wp = Wt + (size_t)n * K + k;
            if (kvec) w = *(const us4*)wp;
            else {
                w.x = wp[0];
                if (k + 1 < K) w.y = wp[1];
                if (k + 2 < K) w.z = wp[2];
                if (k + 3 < K) w.w = wp[3];
            }
        }
        *(us4*)&Ws_l[n * LSTRW + k] = w;
    }
    if (in_mode) {
        for (int k = tid; k < KSTEPS * 32; k += 256) {
            float mn = 0.f, iv = 1.f;
            if (k < stats_K) {
                float s = in_stats[k], ss = in_stats[stats_K + k];
                mn = s * inv_sM;
                float vr = ss * inv_sM - mn * mn;
                iv = rsqrtf(vr + BN_EPS);
            }
            pm[k] = mn; pv[k] = iv;
        }
    }
    __syncthreads();

    // ---- build A fragments in registers ----
    bf16x8 afrag[2][KSTEPS];
    #pragma unroll
    for (int mt = 0; mt < 2; ++mt) {
        int row = m0 + wave * 32 + mt * 16 + l16;
        const float* ap = A + (size_t)row * lda;
        #pragma unroll
        for (int ks = 0; ks < KSTEPS; ++ks) {
            int kb = ks * 32 + quad * 8;
            float v[8];
            if (kvec) {
                #pragma unroll
                for (int h = 0; h < 2; ++h) {
                    int k = kb + h * 4;
                    const float* p = (k >= ksplit) ? &A2[(size_t)row * 128 + (k - 128)]
                                                   : &ap[k];
                    float4 f = *(const float4*)p;
                    v[h * 4 + 0] = f.x; v[h * 4 + 1] = f.y;
                    v[h * 4 + 2] = f.z; v[h * 4 + 3] = f.w;
                }
            } else {
                #pragma unroll
                for (int j = 0; j < 8; ++j) {
                    int k = kb + j;
                    v[j] = (k < K) ? ap[k] : 0.f;
                }
            }
            if (in_mode) {
                #pragma unroll
                for (int j = 0; j < 8; ++j)
                    v[j] = apply_in(v[j], in_mode, pm[kb + j], pv[kb + j]);
            }
            union { bf16x8 b; unsigned short u[8]; } fr;
            #pragma unroll
            for (int j = 0; j < 8; ++j) fr.u[j] = f2bf(v[j]);
            afrag[mt][ks] = fr.b;
        }
    }

    // ---- MFMA ----
    f32x4 acc[2][NSUB];
    #pragma unroll
    for (int i = 0; i < 2; ++i)
        #pragma unroll
        for (int j = 0; j < NSUB; ++j)
            acc[i][j] = (f32x4){0.f, 0.f, 0.f, 0.f};

    #pragma unroll
    for (int ks = 0; ks < KSTEPS; ++ks) {
        #pragma unroll
        for (int nt = 0; nt < NSUB; ++nt) {
            bf16x8 b = *(const bf16x8*)(const void*)&Ws_l[(nt * 16 + l16) * LSTRW + ks * 32 + quad * 8];
            acc[0][nt] = __builtin_amdgcn_mfma_f32_16x16x32_bf16(afrag[0][ks], b, acc[0][nt], 0, 0, 0);
            acc[1][nt] = __builtin_amdgcn_mfma_f32_16x16x32_bf16(afrag[1][ks], b, acc[1][nt], 0, 0, 0);
        }
    }

    // ---- epilogue ----
    float ls[NSUB], lq[NSUB];
    #pragma unroll
    for (int nt = 0; nt < NSUB; ++nt) { ls[nt] = 0.f; lq[nt] = 0.f; }

    #pragma unroll
    for (int nt = 0; nt < NSUB; ++nt) {
        int col = nt * 16 + l16;
        float bv = bias[col];
        float mx = -INFINITY;
        #pragma unroll
        for (int mt = 0; mt < 2; ++mt) {
            int rbase = m0 + wave * 32 + mt * 16 + quad * 4;
            #pragma unroll
            for (int r = 0; r < 4; ++r) {
                float u = acc[mt][nt][r] + bv;
                if (C) {
                    float wv = out_act ? fmaxf(u, 0.f) : u;
                    C[(size_t)(rbase + r) * NT + col] = wv;
                }
                float ru = fmaxf(u, 0.f);
                if (stats_mode) {
                    float s = (stats_mode == 2) ? ru : u;
                    ls[nt] += s; lq[nt] += s * s;
                }
                if (pool_out) mx = fmaxf(mx, ru);
            }
        }
        if (pool_out) {
            mx = fmaxf(mx, __shfl_xor(mx, 16));
            mx = fmaxf(mx, __shfl_xor(mx, 32));
            if (quad == 0) {
                int graph = (m0 + wave * 32) >> 5;
                pool_out[(size_t)graph * NT + col] = mx;
            }
        }
    }

    if (stats_mode) {
        #pragma unroll
        for (int nt = 0; nt < NSUB; ++nt) {
            float s = ls[nt], q = lq[nt];
            s += __shfl_xor(s, 16); q += __shfl_xor(q, 16);
            s += __shfl_xor(s, 32); q += __shfl_xor(q, 32);
            if (quad == 0) { red[wave][0][nt * 16 + l16] = s; red[wave][1][nt * 16 + l16] = q; }
        }
        __syncthreads();
        if (tid < NT) {
            float s = red[0][0][tid] + red[1][0][tid] + red[2][0][tid] + red[3][0][tid];
            float q = red[0][1][tid] + red[1][1][tid] + red[2][1][tid] + red[3][1][tid];
            unsafeAtomicAdd(&out_stats[tid], s);
            unsafeAtomicAdd(&out_stats[NT + tid], q);
        }
    }
}

// ---------------------------------------------------------------------------
// GIN conv-2 fused: h = bn(relu(u2)) [in_mode=3 via in_stats], agg in LDS
// (block = 4 graphs, 256 block-local edges, LDS float atomics), then
// C = agg(h) @ W + bias with stats of u -> out_stats. K = N = 128. In-place.
// ---------------------------------------------------------------------------
#define AST 36   // LDS fp32 row stride for 32-col chunk (+4 pad)

__launch_bounds__(256)
__global__ void gemm_gin2(const float* __restrict__ A, const unsigned short* __restrict__ Wt,
                          const float* __restrict__ bias, float* __restrict__ C,
                          const int* __restrict__ src, const int* __restrict__ dst,
                          const float* __restrict__ in_stats, float inv_sM,
                          float* __restrict__ out_stats)
{
    __shared__ unsigned short Ws_l[128 * 136];
    __shared__ float xl[128 * AST];
    __shared__ float ac[128 * AST];
    __shared__ float pm[128], pv[128];
    __shared__ int eS[256], eD[256];
    __shared__ float red[4][2][128];

    int tid  = threadIdx.x;
    int wave = tid >> 6;
    int lane = tid & 63;
    int quad = lane >> 4;
    int l16  = lane & 15;
    int m0   = blockIdx.x * 128;
    int g0   = m0 >> 5;

    for (int i = tid; i < 128 * 32; i += 256) {
        int n = i >> 5, k = (i & 31) * 4;
        // careful: i&31 indexes us4 granules (32 per row of 128 shorts)
        n = i / 32; k = (i % 32) * 4;
        *(us4*)&Ws_l[n * 136 + k] = *(const us4*)&Wt[n * 128 + k];
    }
    for (int k = tid; k < 128; k += 256) {
        float s = in_stats[k], ss = in_stats[128 + k];
        float mn = s * inv_sM;
        float vr = ss * inv_sM - mn * mn;
        pm[k] = mn;
        pv[k] = rsqrtf(vr + BN_EPS);
    }
    {
        int gl = tid >> 6, e = tid & 63;
        int ge = (g0 + gl) * 64 + e;
        eS[tid] = src[ge] - (g0 + gl) * 32 + gl * 32;
        eD[tid] = dst[ge] - (g0 + gl) * 32 + gl * 32;
    }
    __syncthreads();

    f32x4 acc[2][8];
    #pragma unroll
    for (int i = 0; i < 2; ++i)
        #pragma unroll
        for (int j = 0; j < 8; ++j)
            acc[i][j] = (f32x4){0.f, 0.f, 0.f, 0.f};

    for (int kc = 0; kc < 4; ++kc) {
        // stage 32 cols: transform (bn of relu) and init both xl and ac
        for (int i = tid; i < 128 * 8; i += 256) {
            int row = i >> 3, f4 = (i & 7) * 4;
            int k = kc * 32 + f4;
            float4 f = *(const float4*)&A[(size_t)(m0 + row) * 128 + k];
            float4 t;
            t.x = (fmaxf(f.x, 0.f) - pm[k])     * pv[k];
            t.y = (fmaxf(f.y, 0.f) - pm[k + 1]) * pv[k + 1];
            t.z = (fmaxf(f.z, 0.f) - pm[k + 2]) * pv[k + 2];
            t.w = (fmaxf(f.w, 0.f) - pm[k + 3]) * pv[k + 3];
            *(float4*)&xl[row * AST + f4] = t;
            *(float4*)&ac[row * AST + f4] = t;
        }
        __syncthreads();
        // scatter-add edges (LDS float atomics, independent ops)
        {
            int c = tid & 31, e0 = tid >> 5;
            for (int e = e0; e < 256; e += 8)
                atomicAdd(&ac[eD[e] * AST + c], xl[eS[e] * AST + c]);
        }
        __syncthreads();
        // fragments + MFMA for this k-step
        bf16x8 afr[2];
        #pragma unroll
        for (int mt = 0; mt < 2; ++mt) {
            const float* p = &ac[(wave * 32 + mt * 16 + l16) * AST + quad * 8];
            union { bf16x8 b; unsigned short u[8]; } fr;
            #pragma unroll
            for (int j = 0; j < 8; ++j) fr.u[j] = f2bf(p[j]);
            afr[mt] = fr.b;
        }
        #pragma unroll
        for (int nt = 0; nt < 8; ++nt) {
            bf16x8 b = *(const bf16x8*)(const void*)&Ws_l[(nt * 16 + l16) * 136 + kc * 32 + quad * 8];
            acc[0][nt] = __builtin_amdgcn_mfma_f32_16x16x32_bf16(afr[0], b, acc[0][nt], 0, 0, 0);
            acc[1][nt] = __builtin_amdgcn_mfma_f32_16x16x32_bf16(afr[1], b, acc[1][nt], 0, 0, 0);
        }
        __syncthreads();   // protect xl/ac before next chunk
    }

    // epilogue: write u3, stats of u (mode 1)
    float ls[8], lq[8];
    #pragma unroll
    for (int nt = 0; nt < 8; ++nt) { ls[nt] = 0.f; lq[nt] = 0.f; }
    #pragma unroll
    for (int nt = 0; nt < 8; ++nt) {
        int col = nt * 16 + l16;
        float bv = bias[col];
        #pragma unroll
        for (int mt = 0; mt < 2; ++mt) {
            int rbase = m0 + wave * 32 + mt * 16 + quad * 4;
            #pragma unroll
            for (int r = 0; r < 4; ++r) {
                float u = acc[mt][nt][r] + bv;
                C[(size_t)(rbase + r) * 128 + col] = u;
                ls[nt] += u; lq[nt] += u * u;
            }
        }
    }
    #pragma unroll
    for (int nt = 0; nt < 8; ++nt) {
        float s = ls[nt], q = lq[nt];
        s += __shfl_xor(s, 16); q += __shfl_xor(q, 16);
        s += __shfl_xor(s, 32); q += __shfl_xor(q, 32);
        if (quad == 0) { red[wave][0][nt * 16 + l16] = s; red[wave][1][nt * 16 + l16] = q; }
    }
    __syncthreads();
    if (tid < 128) {
        float s = red[0][0][tid] + red[1][0][tid] + red[2][0][tid] + red[3][0][tid];
        float q = red[0][1][tid] + red[1][1][tid] + red[2][1][tid] + red[3][1][tid];
        unsafeAtomicAdd(&out_stats[tid], s);
        unsafeAtomicAdd(&out_stats[128 + tid], q);
    }
}

// ---------------------------------------------------------------------------
// Old LDS-staged MFMA GEMM for large-K cell layers (ce1 K=908, ce2 K=516).
// ---------------------------------------------------------------------------
#define KC 64
#define LSTR 72

template<int NT>
__launch_bounds__(256)
__global__ void gemm_mfma(const float* __restrict__ A, const unsigned short* __restrict__ Wt,
                          const float* __restrict__ bias, float* __restrict__ C,
                          int M, int K, int N,
                          const float* __restrict__ in_stats, float inv_sM, int in_mode,
                          float* __restrict__ out_stats, int stats_mode, int out_act)
{
    __shared__ unsigned short As_l[128 * LSTR];
    __shared__ unsigned short Ws_l[NT * LSTR];
    __shared__ float pm[920], pv[920];
    __shared__ float red[4][2][NT];

    constexpr int NSUB = NT / 16;
    int tid  = threadIdx.x;
    int wave = tid >> 6;
    int lane = tid & 63;
    int quad = lane >> 4;
    int l16  = lane & 15;
    int m0 = blockIdx.x * 128;
    int n0 = blockIdx.y * NT;

    if (in_mode) {
        for (int k = tid; k < K; k += 256) {
            float s = in_stats[k], ss = in_stats[K + k];
            float mn = s * inv_sM;
            float vr = ss * inv_sM - mn * mn;
            pm[k] = mn;
            pv[k] = rsqrtf(vr + BN_EPS);
        }
        __syncthreads();
    }

    f32x4 acc[2][NSUB];
    #pragma unroll
    for (int i = 0; i < 2; ++i)
        #pragma unroll
        for (int j = 0; j < NSUB; ++j)
            acc[i][j] = (f32x4){0.f, 0.f, 0.f, 0.f};

    const bool vec_ok = ((K & 3) == 0);

    for (int k0 = 0; k0 < K; k0 += KC) {
        for (int i = tid; i < 128 * 16; i += 256) {
            int row = i >> 4, f4 = i & 15;
            int k = k0 + f4 * 4;
            float v0 = 0.f, v1 = 0.f, v2 = 0.f, v3 = 0.f;
            if (k < K) {
                const float* ap = A + (size_t)(m0 + row) * K + k;
                if (vec_ok) {
                    float4 f = *(const float4*)ap;
                    v0 = f.x; v1 = f.y; v2 = f.z; v3 = f.w;
                } else {
                    v0 = ap[0];
                    if (k + 1 < K) v1 = ap[1];
                    if (k + 2 < K) v2 = ap[2];
                    if (k + 3 < K) v3 = ap[3];
                }
                if (in_mode) {
                    v0 = apply_in(v0, in_mode, pm[k], pv[k]);
                    if (k + 1 < K) v1 = apply_in(v1, in_mode, pm[k + 1], pv[k + 1]);
                    if (k + 2 < K) v2 = apply_in(v2, in_mode, pm[k + 2], pv[k + 2]);
                    if (k + 3 < K) v3 = apply_in(v3, in_mode, pm[k + 3], pv[k + 3]);
                }
            }
            us4 w4 = { f2bf(v0), f2bf(v1), f2bf(v2), f2bf(v3) };
            if (k >= K) w4 = (us4){0, 0, 0, 0};
            *(us4*)&As_l[row * LSTR + f4 * 4] = w4;
        }
        for (int i = tid; i < NT * 16; i += 256) {
            int nn = i >> 4, kt = i & 15;
            int k = k0 + kt * 4;
            int gn = n0 + nn;
            us4 w4 = (us4){0, 0, 0, 0};
            if (gn < N && k < K) {
                const unsigned short* wp = Wt + (size_t)gn * K + k;
                if (vec_ok) {
                    w4 = *(const us4*)wp;
                } else {
                    w4.x = wp[0];
                    if (k + 1 < K) w4.y = wp[1];
                    if (k + 2 < K) w4.z = wp[2];
                    if (k + 3 < K) w4.w = wp[3];
                }
            }
            *(us4*)&Ws_l[nn * LSTR + kt * 4] = w4;
        }
        __syncthreads();

        int mbase = wave * 32;
        #pragma unroll
        for (int ks = 0; ks < 2; ++ks) {
            bf16x8 a0 = *(const bf16x8*)(const void*)&As_l[(mbase + l16) * LSTR + ks * 32 + quad * 8];
            bf16x8 a1 = *(const bf16x8*)(const void*)&As_l[(mbase + 16 + l16) * LSTR + ks * 32 + quad * 8];
            #pragma unroll
            for (int nt = 0; nt < NSUB; ++nt) {
                bf16x8 b = *(const bf16x8*)(const void*)&Ws_l[(nt * 16 + l16) * LSTR + ks * 32 + quad * 8];
                acc[0][nt] = __builtin_amdgcn_mfma_f32_16x16x32_bf16(a0, b, acc[0][nt], 0, 0, 0);
                acc[1][nt] = __builtin_amdgcn_mfma_f32_16x16x32_bf16(a1, b, acc[1][nt], 0, 0, 0);
            }
        }
        __syncthreads();
    }

    float ls[NSUB], lq[NSUB];
    #pragma unroll
    for (int nt = 0; nt < NSUB; ++nt) { ls[nt] = 0.f; lq[nt] = 0.f; }

    #pragma unroll
    for (int mt = 0; mt < 2; ++mt) {
        int rbase = m0 + wave * 32 + mt * 16 + quad * 4;
        #pragma unroll
        for (int nt = 0; nt < NSUB; ++nt) {
            int col = n0 + nt * 16 + l16;
            if (col < N) {
                float bv = bias[col];
                #pragma unroll
                for (int r = 0; r < 4; ++r) {
                    float u = acc[mt][nt][r] + bv;
                    float wv = out_act ? fmaxf(u, 0.f) : u;
                    C[(size_t)(rbase + r) * N + col] = wv;
                    if (stats_mode) {
                        float v = (stats_mode == 2) ? fmaxf(u, 0.f) : u;
                        ls[nt] += v; lq[nt] += v * v;
                    }
                }
            }
        }
    }

    if (stats_mode) {
        #pragma unroll
        for (int nt = 0; nt < NSUB; ++nt) {
            float s = ls[nt], q = lq[nt];
            s += __shfl_xor(s, 16); q += __shfl_xor(q, 16);
            s += __shfl_xor(s, 32); q += __shfl_xor(q, 32);
            if (quad == 0) { red[wave][0][nt * 16 + l16] = s; red[wave][1][nt * 16 + l16] = q; }
        }
        __syncthreads();
        if (tid < NT) {
            int col = n0 + tid;
            if (col < N) {
                float s = red[0][0][tid] + red[1][0][tid] + red[2][0][tid] + red[3][0][tid];
                float q = red[0][1][tid] + red[1][1][tid] + red[2][1][tid] + red[3][1][tid];
                unsafeAtomicAdd(&out_stats[col], s);
                unsafeAtomicAdd(&out_stats[N + col], q);
            }
        }
    }
}

// ---------------------------------------------------------------------------
// GIN conv-1 input aggregation (F=9, cheap): out = x + segment_sum(x[src],dst)
// ---------------------------------------------------------------------------
__global__ void gin_agg9(const float* __restrict__ x, const int* __restrict__ src,
                         const int* __restrict__ dst, float* __restrict__ out)
{
    const int F = 9;
    __shared__ float xl[32 * F];
    __shared__ float acb[32 * F];
    __shared__ int es[EPG], ed[EPG];
    int g = blockIdx.x;
    int tid = threadIdx.x;
    size_t base = (size_t)g * 32 * F;
    for (int i = tid; i < 32 * F; i += blockDim.x) {
        float v = x[base + i];
        xl[i] = v;
        acb[i] = v;
    }
    if (tid < EPG) {
        es[tid] = src[g * EPG + tid] - g * NPG;
        ed[tid] = dst[g * EPG + tid] - g * NPG;
    }
    __syncthreads();
    if (tid < 64) {
        int e = tid;
        // parallel over edges with LDS atomics (9 cols each)
        for (int c = 0; c < F; ++c)
            atomicAdd(&acb[ed[e] * F + c], xl[es[e] * F + c]);
    }
    __syncthreads();
    for (int i = tid; i < 32 * F; i += blockDim.x)
        out[base + i] = acb[i];
}

// ---------------------------------------------------------------------------
// Final: y[i] = elu(bn(u[i,:])) . w + b   (K = 64)
// ---------------------------------------------------------------------------
__global__ void final_dot(const float* __restrict__ u, const float* __restrict__ w,
                          const float* __restrict__ b, float* __restrict__ y,
                          const float* __restrict__ stats, float inv_sM)
{
    __shared__ float pmv[64], piv[64], sw[64];
    int tid = threadIdx.x;
    if (tid < 64) {
        float s = stats[tid], ss = stats[64 + tid];
        float mn = s * inv_sM;
        float vr = ss * inv_sM - mn * mn;
        pmv[tid] = mn;
        piv[tid] = rsqrtf(vr + BN_EPS);
        sw[tid] = w[tid];
    }
    __syncthreads();
    int i = blockIdx.x * blockDim.x + tid;
    if (i >= BGRAPH) return;
    float acc = 0.f;
    #pragma unroll
    for (int k = 0; k < 64; ++k) {
        float v = (u[(size_t)i * 64 + k] - pmv[k]) * piv[k];
        v = (v > 0.f) ? v : expm1f(v);
        acc += v * sw[k];
    }
    y[i] = acc + b[0];
}

// ---------------------------------------------------------------------------
// Host driver. 15 launches, ~146 MB workspace.
// ---------------------------------------------------------------------------
extern "C" void kernel_launch(void* const* d_in, const int* in_sizes, int n_in,
                              void* d_out, int out_size, void* d_ws, size_t ws_size,
                              hipStream_t stream)
{
    const float* cell   = (const float*)d_in[0];
    const float* drug_x = (const float*)d_in[1];
    const int*   eidx   = (const int*)d_in[2];
    const float* ce1w = (const float*)d_in[4];  const float* ce1b = (const float*)d_in[5];
    const float* ce2w = (const float*)d_in[6];  const float* ce2b = (const float*)d_in[7];
    const float* ce3w = (const float*)d_in[8];  const float* ce3b = (const float*)d_in[9];
    const float* g11w = (const float*)d_in[10]; const float* g11b = (const float*)d_in[11];
    const float* g12w = (const float*)d_in[12]; const float* g12b = (const float*)d_in[13];
    const float* g21w = (const float*)d_in[14]; const float* g21b = (const float*)d_in[15];
    const float* g22w = (const float*)d_in[16]; const float* g22b = (const float*)d_in[17];
    const float* d1w  = (const float*)d_in[18]; const float* d1b  = (const float*)d_in[19];
    const float* d2w  = (const float*)d_in[20]; const float* d2b  = (const float*)d_in[21];
    const float* f1w  = (const float*)d_in[22]; const float* f1b  = (const float*)d_in[23];
    const float* f2w  = (const float*)d_in[24]; const float* f2b  = (const float*)d_in[25];
    const float* f3w  = (const float*)d_in[26]; const float* f3b  = (const float*)d_in[27];

    const int* src = eidx;
    const int* dst = eidx + NEDGE;
    float* out = (float*)d_out;

    const float INV_N = 1.f / (float)NNODE;
    const float INV_B = 1.f / (float)BGRAPH;
    const int KBIG = 1 << 30;

    // ---- workspace layout ----
    float* ws   = (float*)d_ws;
    float* big  = ws;                                   // NNODE*128 floats
    float* aux  = ws + (size_t)NNODE * 128;             // NNODE*9 floats
    float* sb   = aux + (size_t)NNODE * 9;              // 10*1032 stats floats
    unsigned short* wtb = (unsigned short*)(sb + 10 * 1032);
    auto ST = [&](int i) { return sb + (size_t)i * 1032; };
    float* st_u1    = ST(0);
    float* st_u2rel = ST(1);
    float* st_u3    = ST(2);
    float* st_u4rel = ST(3);
    float* st_c1    = ST(4);
    float* st_c2    = ST(5);
    float* st_c3    = ST(6);
    float* st_d1    = ST(7);
    float* st_f1    = ST(8);
    float* st_f2    = ST(9);

    struct WDef { const float* w; int K; int N; };
    WDef wd[11] = {
        {ce1w, CELLD, 516}, {ce2w, 516, 256}, {ce3w, 256, 128},
        {g11w, 9, 128}, {g12w, 128, 128}, {g21w, 128, 128}, {g22w, 128, 128},
        {d1w, 128, 128}, {d2w, 128, 128}, {f1w, 256, 128}, {f2w, 128, 64}
    };
    TArgs ta;
    int off = 0;
    unsigned short* wt[11];
    for (int i = 0; i < 11; ++i) {
        wt[i] = wtb + off;
        ta.s[i] = TSeg{ wd[i].w, wt[i], wd[i].K, wd[i].N, off };
        off += wd[i].K * wd[i].N;
    }
    ta.total = off;

    // small buffers inside `big` (used only after GIN branch is done with it)
    float* c1    = big;
    float* c2    = c1 + (size_t)BGRAPH * 516;
    float* c3u   = c2 + (size_t)BGRAPH * 256;
    float* dbuf  = c3u + (size_t)BGRAPH * 128;
    float* d2buf = dbuf + (size_t)BGRAPH * 128;
    float* f1o   = d2buf + (size_t)BGRAPH * 128;
    float* f2o   = f1o + (size_t)BGRAPH * 128;
    float* pbuf  = aux;   // reused once g11 consumed aux

    zero_buf<<<(10 * 1032 + 255) / 256, 256, 0, stream>>>(sb, 10 * 1032);
    transpose_w<<<(ta.total + 255) / 256, 256, 0, stream>>>(ta);

    // ================= GIN branch (in-place in `big`) ========================
    gin_agg9<<<BGRAPH, 128, 0, stream>>>(drug_x, src, dst, aux);
    // g11: K=9
    gemm_rA<1, 128><<<NNODE / 128, 256, 0, stream>>>(
        aux, nullptr, 9, 9, 9, KBIG, wt[3], g11b, big,
        nullptr, 0.f, 0, st_u1, 1, 0, nullptr);
    // g12: relu(bn(u1)) @ W, stats of relu(u2)
    gemm_rA<4, 128><<<NNODE / 128, 256, 0, stream>>>(
        big, nullptr, 128, 128, 128, KBIG, wt[4], g12b, big,
        st_u1, INV_N, 1, st_u2rel, 2, 0, nullptr);
    // g21: fused h=bn(relu(u2)), agg, GEMM, stats of u3
    gemm_gin2<<<NNODE / 128, 256, 0, stream>>>(
        big, wt[5], g21b, big, src, dst, st_u2rel, INV_N, st_u3);
    // g22: relu(bn(u3)) @ W; NO C write; stats of relu(u4); pool max(relu(u4))
    gemm_rA<4, 128><<<NNODE / 128, 256, 0, stream>>>(
        big, nullptr, 128, 128, 128, KBIG, wt[6], g22b, nullptr,
        st_u3, INV_N, 1, st_u4rel, 2, 0, pbuf);

    // ================= cell branch ===========================================
    gemm_mfma<128><<<dim3(BGRAPH / 128, 5), 256, 0, stream>>>(
        cell, wt[0], ce1b, c1, BGRAPH, CELLD, 516, nullptr, 0.f, 0, st_c1, 1, 0);
    gemm_mfma<128><<<dim3(BGRAPH / 128, 2), 256, 0, stream>>>(
        c1, wt[1], ce2b, c2, BGRAPH, 516, 256, st_c1, INV_B, 1, st_c2, 1, 0);
    gemm_rA<8, 128><<<BGRAPH / 128, 256, 0, stream>>>(
        c2, nullptr, 256, 256, 256, KBIG, wt[2], ce3b, c3u,
        st_c2, INV_B, 1, st_c3, 1, 0, nullptr);

    // ================= d branch ==============================================
    // d1: input = bn(pool) via in_mode=3 with NNODE relu-stats
    gemm_rA<4, 128><<<BGRAPH / 128, 256, 0, stream>>>(
        pbuf, nullptr, 128, 128, 128, KBIG, wt[7], d1b, dbuf,
        st_u4rel, INV_N, 3, st_d1, 1, 0, nullptr);
    gemm_rA<4, 128><<<BGRAPH / 128, 256, 0, stream>>>(
        dbuf, nullptr, 128, 128, 128, KBIG, wt[8], d2b, d2buf,
        st_d1, INV_B, 1, nullptr, 0, 1, nullptr);

    // ================= head ==================================================
    // f1: dual-source A = [bn-relu(c3u) | d2buf(raw, >=0)], split at k=128
    gemm_rA<8, 128><<<BGRAPH / 128, 256, 0, stream>>>(
        c3u, d2buf, 128, 256, 128, 128, wt[9], f1b, f1o,
        st_c3, INV_B, 1, st_f1, 1, 0, nullptr);
    gemm_rA<4, 64><<<BGRAPH / 128, 256, 0, stream>>>(
        f1o, nullptr, 128, 128, 128, KBIG, wt[10], f2b, f2o,
        st_f1, INV_B, 2, st_f2, 1, 0, nullptr);
    final_dot<<<BGRAPH / 256, 256, 0, stream>>>(f2o, f3w, f3b, out, st_f2, INV_B);
}

// Round 6
// 910.156 us; speedup vs baseline: 1.3161x; 1.3161x over previous
//
#include <hip/hip_runtime.h>
#include <hip/hip_bf16.h>
#include <math.h>

// Problem constants (from reference)
#define BGRAPH 8192
#define NPG 32
#define EPG 64
#define NNODE (BGRAPH * NPG)   // 262144
#define NEDGE (BGRAPH * EPG)   // 524288
#define CELLD 908
#define BN_EPS 1e-5f

typedef __attribute__((ext_vector_type(8))) short bf16x8;   // 8 bf16 = 4 VGPRs
typedef __attribute__((ext_vector_type(4))) float f32x4;
typedef __attribute__((ext_vector_type(4))) unsigned short us4;

__device__ __forceinline__ unsigned short f2bf(float f)
{
    unsigned int u = __float_as_uint(f);
    u = (u + 0x7FFFu + ((u >> 16) & 1u)) >> 16;   // RNE
    return (unsigned short)u;
}

// in_mode: 0=raw, 1=relu((x-m)*iv), 2=elu((x-m)*iv), 3=(relu(x)-m)*iv
__device__ __forceinline__ float apply_in(float v, int mode, float mn, float iv)
{
    if (mode == 1)      { v = (v - mn) * iv; v = fmaxf(v, 0.f); }
    else if (mode == 2) { v = (v - mn) * iv; v = (v > 0.f) ? v : expm1f(v); }
    else if (mode == 3) { v = fmaxf(v, 0.f); v = (v - mn) * iv; }
    return v;
}

__global__ void zero_buf(float* __restrict__ p, int n)
{
    int i = blockIdx.x * blockDim.x + threadIdx.x;
    if (i < n) p[i] = 0.f;
}

// ---------------------------------------------------------------------------
// Fused weight transpose+convert: wt[n*K+k] = bf16(w[k*N+n]) for 11 layers.
// ---------------------------------------------------------------------------
struct TSeg { const float* w; unsigned short* wt; int K; int N; int off; };
struct TArgs { TSeg s[11]; int total; };

__global__ void transpose_w(TArgs a)
{
    int i = blockIdx.x * blockDim.x + threadIdx.x;
    if (i >= a.total) return;
    int j = 0;
    while (j < 10 && i >= a.s[j + 1].off) ++j;
    int idx = i - a.s[j].off;
    int K = a.s[j].K, N = a.s[j].N;
    int n = idx / K, k = idx - n * K;
    a.s[j].wt[idx] = f2bf(a.s[j].w[(size_t)k * N + n]);
}

// ---------------------------------------------------------------------------
// Per-graph in-edge CSR: row_start[g*33 + 0..32], col_idx[g*64 + ...] = local
// src of edges sorted by local dst. One 64-thread block per graph.
// ---------------------------------------------------------------------------
__global__ void csr_build(const int* __restrict__ src, const int* __restrict__ dst,
                          int* __restrict__ row_start, int* __restrict__ col_idx)
{
    __shared__ int cnt[32], fill[32], rs[33];
    int g = blockIdx.x;
    int tid = threadIdx.x;   // 0..63
    if (tid < 32) { cnt[tid] = 0; fill[tid] = 0; }
    __syncthreads();
    int s = src[g * EPG + tid] - g * NPG;
    int d = dst[g * EPG + tid] - g * NPG;
    atomicAdd(&cnt[d], 1);
    __syncthreads();
    if (tid == 0) {
        int acc = 0;
        for (int i = 0; i < 32; ++i) { rs[i] = acc; acc += cnt[i]; }
        rs[32] = acc;
    }
    __syncthreads();
    int pos = rs[d] + atomicAdd(&fill[d], 1);
    col_idx[g * EPG + pos] = s;
    if (tid < 33) row_start[g * 33 + tid] = rs[tid];
}

// ---------------------------------------------------------------------------
// GIN aggregation by GATHER (F=128): out[n,c] = f(x)[n,c] + sum_{j in in(n)}
// f(x)[src_j,c], f = bn(relu(.)) via in_stats (in_mode=3). One graph per
// block, 256 threads, 16 KB LDS. In-place safe (reads staged before writes).
// ---------------------------------------------------------------------------
__global__ void gin_gather(const float* __restrict__ x,
                           const int* __restrict__ row_start,
                           const int* __restrict__ col_idx,
                           float* __restrict__ out,
                           const float* __restrict__ in_stats, float inv_sM)
{
    __shared__ float xl[32 * 128];
    __shared__ float pm[128], pv[128];
    __shared__ int rs[33], ci[64];
    int g = blockIdx.x;
    int tid = threadIdx.x;

    if (tid < 128) {
        float s = in_stats[tid], ss = in_stats[128 + tid];
        float mn = s * inv_sM;
        float vr = ss * inv_sM - mn * mn;
        pm[tid] = mn;
        pv[tid] = rsqrtf(vr + BN_EPS);
    } else if (tid < 161) {
        rs[tid - 128] = row_start[g * 33 + (tid - 128)];
    } else if (tid < 225) {
        ci[tid - 161] = col_idx[g * EPG + (tid - 161)];
    }
    __syncthreads();

    size_t base = (size_t)g * 32 * 128;
    // stage + transform: 1024 float4, 4 per thread
    for (int i = tid; i < 32 * 32; i += 256) {
        float4 f = *(const float4*)&x[base + i * 4];
        int c = (i & 31) * 4;
        float4 t;
        t.x = (fmaxf(f.x, 0.f) - pm[c])     * pv[c];
        t.y = (fmaxf(f.y, 0.f) - pm[c + 1]) * pv[c + 1];
        t.z = (fmaxf(f.z, 0.f) - pm[c + 2]) * pv[c + 2];
        t.w = (fmaxf(f.w, 0.f) - pm[c + 3]) * pv[c + 3];
        *(float4*)&xl[i * 4] = t;
    }
    __syncthreads();

    int c = tid & 127;
    int h = tid >> 7;          // 0 or 1
    #pragma unroll
    for (int i = 0; i < 16; ++i) {
        int n = h * 16 + i;    // wave-uniform
        float a = xl[n * 128 + c];
        int e0 = rs[n], e1 = rs[n + 1];
        for (int j = e0; j < e1; ++j)
            a += xl[ci[j] * 128 + c];
        out[base + n * 128 + c] = a;
    }
}

// ---------------------------------------------------------------------------
// Register-A MFMA GEMM. Tile 128 x NT, K <= KSTEPS*32 (K in {9,128,256}),
// N == NT. W resident in LDS once (no K-loop). A loaded directly to regs,
// BN transform fused on load. Optional: dual A source (f1 concat), skip C,
// column stats of u / relu(u), per-graph max-pool of relu(u) (wave==graph).
// In-place safe. M must be a multiple of 128.
// ---------------------------------------------------------------------------
template<int KSTEPS, int NT>
__launch_bounds__(256)
__global__ void gemm_rA(const float* __restrict__ A, const float* __restrict__ A2,
                        int lda, int K, int stats_K, int ksplit,
                        const unsigned short* __restrict__ Wt,
                        const float* __restrict__ bias, float* __restrict__ C,
                        const float* __restrict__ in_stats, float inv_sM, int in_mode,
                        float* __restrict__ out_stats, int stats_mode, int out_act,
                        float* __restrict__ pool_out)
{
    constexpr int LSTRW = KSTEPS * 32 + 8;   // LDS row stride (ushorts)
    constexpr int NSUB = NT / 16;
    __shared__ unsigned short Ws_l[NT * LSTRW];
    __shared__ float pm[KSTEPS * 32], pv[KSTEPS * 32];
    __shared__ float red[4][2][NT];

    int tid  = threadIdx.x;
    int wave = tid >> 6;
    int lane = tid & 63;
    int quad = lane >> 4;
    int l16  = lane & 15;
    int m0   = blockIdx.x * 128;

    // ---- stage W (full K) and BN params ----
    const bool kvec = ((K & 3) == 0);
    for (int i = tid; i < NT * (KSTEPS * 8); i += 256) {
        int n = i / (KSTEPS * 8), g4 = i % (KSTEPS * 8);
        int k = g4 * 4;
        us4 w = (us4){0, 0, 0, 0};
        if (k < K) {
            const unsigned short* wp = Wt + (size_t)n * K + k;
            if (kvec) w = *(const us4*)wp;
            else {
                w.x = wp[0];
                if (k + 1 < K) w.y = wp[1];
                if (k + 2 < K) w.z = wp[2];
                if (k + 3 < K) w.w = wp[3];
            }
        }
        *(us4*)&Ws_l[n * LSTRW + k] = w;
    }
    if (in_mode) {
        for (int k = tid; k < KSTEPS * 32; k += 256) {
            float mn = 0.f, iv = 1.f;
            if (k < stats_K) {
                float s = in_stats[k], ss = in_stats[stats_K + k];
                mn = s * inv_sM;
                float vr = ss * inv_sM - mn * mn;
                iv = rsqrtf(vr + BN_EPS);
            }
            pm[k] = mn; pv[k] = iv;
        }
    }
    __syncthreads();

    // ---- build A fragments in registers ----
    bf16x8 afrag[2][KSTEPS];
    #pragma unroll
    for (int mt = 0; mt < 2; ++mt) {
        int row = m0 + wave * 32 + mt * 16 + l16;
        const float* ap = A + (size_t)row * lda;
        #pragma unroll
        for (int ks = 0; ks < KSTEPS; ++ks) {
            int kb = ks * 32 + quad * 8;
            float v[8];
            if (kvec) {
                #pragma unroll
                for (int h = 0; h < 2; ++h) {
                    int k = kb + h * 4;
                    const float* p = (k >= ksplit) ? &A2[(size_t)row * 128 + (k - 128)]
                                                   : &ap[k];
                    float4 f = *(const float4*)p;
                    v[h * 4 + 0] = f.x; v[h * 4 + 1] = f.y;
                    v[h * 4 + 2] = f.z; v[h * 4 + 3] = f.w;
                }
            } else {
                #pragma unroll
                for (int j = 0; j < 8; ++j) {
                    int k = kb + j;
                    v[j] = (k < K) ? ap[k] : 0.f;
                }
            }
            if (in_mode) {
                #pragma unroll
                for (int j = 0; j < 8; ++j)
                    v[j] = apply_in(v[j], in_mode, pm[kb + j], pv[kb + j]);
            }
            union { bf16x8 b; unsigned short u[8]; } fr;
            #pragma unroll
            for (int j = 0; j < 8; ++j) fr.u[j] = f2bf(v[j]);
            afrag[mt][ks] = fr.b;
        }
    }

    // ---- MFMA ----
    f32x4 acc[2][NSUB];
    #pragma unroll
    for (int i = 0; i < 2; ++i)
        #pragma unroll
        for (int j = 0; j < NSUB; ++j)
            acc[i][j] = (f32x4){0.f, 0.f, 0.f, 0.f};

    #pragma unroll
    for (int ks = 0; ks < KSTEPS; ++ks) {
        #pragma unroll
        for (int nt = 0; nt < NSUB; ++nt) {
            bf16x8 b = *(const bf16x8*)(const void*)&Ws_l[(nt * 16 + l16) * LSTRW + ks * 32 + quad * 8];
            acc[0][nt] = __builtin_amdgcn_mfma_f32_16x16x32_bf16(afrag[0][ks], b, acc[0][nt], 0, 0, 0);
            acc[1][nt] = __builtin_amdgcn_mfma_f32_16x16x32_bf16(afrag[1][ks], b, acc[1][nt], 0, 0, 0);
        }
    }

    // ---- epilogue ----
    float ls[NSUB], lq[NSUB];
    #pragma unroll
    for (int nt = 0; nt < NSUB; ++nt) { ls[nt] = 0.f; lq[nt] = 0.f; }

    #pragma unroll
    for (int nt = 0; nt < NSUB; ++nt) {
        int col = nt * 16 + l16;
        float bv = bias[col];
        float mx = -INFINITY;
        #pragma unroll
        for (int mt = 0; mt < 2; ++mt) {
            int rbase = m0 + wave * 32 + mt * 16 + quad * 4;
            #pragma unroll
            for (int r = 0; r < 4; ++r) {
                float u = acc[mt][nt][r] + bv;
                if (C) {
                    float wv = out_act ? fmaxf(u, 0.f) : u;
                    C[(size_t)(rbase + r) * NT + col] = wv;
                }
                float ru = fmaxf(u, 0.f);
                if (stats_mode) {
                    float s = (stats_mode == 2) ? ru : u;
                    ls[nt] += s; lq[nt] += s * s;
                }
                if (pool_out) mx = fmaxf(mx, ru);
            }
        }
        if (pool_out) {
            mx = fmaxf(mx, __shfl_xor(mx, 16));
            mx = fmaxf(mx, __shfl_xor(mx, 32));
            if (quad == 0) {
                int graph = (m0 + wave * 32) >> 5;
                pool_out[(size_t)graph * NT + col] = mx;
            }
        }
    }

    if (stats_mode) {
        #pragma unroll
        for (int nt = 0; nt < NSUB; ++nt) {
            float s = ls[nt], q = lq[nt];
            s += __shfl_xor(s, 16); q += __shfl_xor(q, 16);
            s += __shfl_xor(s, 32); q += __shfl_xor(q, 32);
            if (quad == 0) { red[wave][0][nt * 16 + l16] = s; red[wave][1][nt * 16 + l16] = q; }
        }
        __syncthreads();
        if (tid < NT) {
            float s = red[0][0][tid] + red[1][0][tid] + red[2][0][tid] + red[3][0][tid];
            float q = red[0][1][tid] + red[1][1][tid] + red[2][1][tid] + red[3][1][tid];
            unsafeAtomicAdd(&out_stats[tid], s);
            unsafeAtomicAdd(&out_stats[NT + tid], q);
        }
    }
}

// ---------------------------------------------------------------------------
// LDS-staged MFMA GEMM for large-K cell layers (ce1 K=908, ce2 K=516).
// ---------------------------------------------------------------------------
#define KC 64
#define LSTR 72

template<int NT>
__launch_bounds__(256)
__global__ void gemm_mfma(const float* __restrict__ A, const unsigned short* __restrict__ Wt,
                          const float* __restrict__ bias, float* __restrict__ C,
                          int M, int K, int N,
                          const float* __restrict__ in_stats, float inv_sM, int in_mode,
                          float* __restrict__ out_stats, int stats_mode, int out_act)
{
    __shared__ unsigned short As_l[128 * LSTR];
    __shared__ unsigned short Ws_l[NT * LSTR];
    __shared__ float pm[920], pv[920];
    __shared__ float red[4][2][NT];

    constexpr int NSUB = NT / 16;
    int tid  = threadIdx.x;
    int wave = tid >> 6;
    int lane = tid & 63;
    int quad = lane >> 4;
    int l16  = lane & 15;
    int m0 = blockIdx.x * 128;
    int n0 = blockIdx.y * NT;

    if (in_mode) {
        for (int k = tid; k < K; k += 256) {
            float s = in_stats[k], ss = in_stats[K + k];
            float mn = s * inv_sM;
            float vr = ss * inv_sM - mn * mn;
            pm[k] = mn;
            pv[k] = rsqrtf(vr + BN_EPS);
        }
        __syncthreads();
    }

    f32x4 acc[2][NSUB];
    #pragma unroll
    for (int i = 0; i < 2; ++i)
        #pragma unroll
        for (int j = 0; j < NSUB; ++j)
            acc[i][j] = (f32x4){0.f, 0.f, 0.f, 0.f};

    const bool vec_ok = ((K & 3) == 0);

    for (int k0 = 0; k0 < K; k0 += KC) {
        for (int i = tid; i < 128 * 16; i += 256) {
            int row = i >> 4, f4 = i & 15;
            int k = k0 + f4 * 4;
            float v0 = 0.f, v1 = 0.f, v2 = 0.f, v3 = 0.f;
            if (k < K) {
                const float* ap = A + (size_t)(m0 + row) * K + k;
                if (vec_ok) {
                    float4 f = *(const float4*)ap;
                    v0 = f.x; v1 = f.y; v2 = f.z; v3 = f.w;
                } else {
                    v0 = ap[0];
                    if (k + 1 < K) v1 = ap[1];
                    if (k + 2 < K) v2 = ap[2];
                    if (k + 3 < K) v3 = ap[3];
                }
                if (in_mode) {
                    v0 = apply_in(v0, in_mode, pm[k], pv[k]);
                    if (k + 1 < K) v1 = apply_in(v1, in_mode, pm[k + 1], pv[k + 1]);
                    if (k + 2 < K) v2 = apply_in(v2, in_mode, pm[k + 2], pv[k + 2]);
                    if (k + 3 < K) v3 = apply_in(v3, in_mode, pm[k + 3], pv[k + 3]);
                }
            }
            us4 w4 = { f2bf(v0), f2bf(v1), f2bf(v2), f2bf(v3) };
            if (k >= K) w4 = (us4){0, 0, 0, 0};
            *(us4*)&As_l[row * LSTR + f4 * 4] = w4;
        }
        for (int i = tid; i < NT * 16; i += 256) {
            int nn = i >> 4, kt = i & 15;
            int k = k0 + kt * 4;
            int gn = n0 + nn;
            us4 w4 = (us4){0, 0, 0, 0};
            if (gn < N && k < K) {
                const unsigned short* wp = Wt + (size_t)gn * K + k;
                if (vec_ok) {
                    w4 = *(const us4*)wp;
                } else {
                    w4.x = wp[0];
                    if (k + 1 < K) w4.y = wp[1];
                    if (k + 2 < K) w4.z = wp[2];
                    if (k + 3 < K) w4.w = wp[3];
                }
            }
            *(us4*)&Ws_l[nn * LSTR + kt * 4] = w4;
        }
        __syncthreads();

        int mbase = wave * 32;
        #pragma unroll
        for (int ks = 0; ks < 2; ++ks) {
            bf16x8 a0 = *(const bf16x8*)(const void*)&As_l[(mbase + l16) * LSTR + ks * 32 + quad * 8];
            bf16x8 a1 = *(const bf16x8*)(const void*)&As_l[(mbase + 16 + l16) * LSTR + ks * 32 + quad * 8];
            #pragma unroll
            for (int nt = 0; nt < NSUB; ++nt) {
                bf16x8 b = *(const bf16x8*)(const void*)&Ws_l[(nt * 16 + l16) * LSTR + ks * 32 + quad * 8];
                acc[0][nt] = __builtin_amdgcn_mfma_f32_16x16x32_bf16(a0, b, acc[0][nt], 0, 0, 0);
                acc[1][nt] = __builtin_amdgcn_mfma_f32_16x16x32_bf16(a1, b, acc[1][nt], 0, 0, 0);
            }
        }
        __syncthreads();
    }

    float ls[NSUB], lq[NSUB];
    #pragma unroll
    for (int nt = 0; nt < NSUB; ++nt) { ls[nt] = 0.f; lq[nt] = 0.f; }

    #pragma unroll
    for (int mt = 0; mt < 2; ++mt) {
        int rbase = m0 + wave * 32 + mt * 16 + quad * 4;
        #pragma unroll
        for (int nt = 0; nt < NSUB; ++nt) {
            int col = n0 + nt * 16 + l16;
            if (col < N) {
                float bv = bias[col];
                #pragma unroll
                for (int r = 0; r < 4; ++r) {
                    float u = acc[mt][nt][r] + bv;
                    float wv = out_act ? fmaxf(u, 0.f) : u;
                    C[(size_t)(rbase + r) * N + col] = wv;
                    if (stats_mode) {
                        float v = (stats_mode == 2) ? fmaxf(u, 0.f) : u;
                        ls[nt] += v; lq[nt] += v * v;
                    }
                }
            }
        }
    }

    if (stats_mode) {
        #pragma unroll
        for (int nt = 0; nt < NSUB; ++nt) {
            float s = ls[nt], q = lq[nt];
            s += __shfl_xor(s, 16); q += __shfl_xor(q, 16);
            s += __shfl_xor(s, 32); q += __shfl_xor(q, 32);
            if (quad == 0) { red[wave][0][nt * 16 + l16] = s; red[wave][1][nt * 16 + l16] = q; }
        }
        __syncthreads();
        if (tid < NT) {
            int col = n0 + tid;
            if (col < N) {
                float s = red[0][0][tid] + red[1][0][tid] + red[2][0][tid] + red[3][0][tid];
                float q = red[0][1][tid] + red[1][1][tid] + red[2][1][tid] + red[3][1][tid];
                unsafeAtomicAdd(&out_stats[col], s);
                unsafeAtomicAdd(&out_stats[N + col], q);
            }
        }
    }
}

// ---------------------------------------------------------------------------
// GIN conv-1 input aggregation (F=9, cheap): out = x + segment_sum(x[src],dst)
// ---------------------------------------------------------------------------
__global__ void gin_agg9(const float* __restrict__ x, const int* __restrict__ src,
                         const int* __restrict__ dst, float* __restrict__ out)
{
    const int F = 9;
    __shared__ float xl[32 * F];
    __shared__ float acb[32 * F];
    __shared__ int es[EPG], ed[EPG];
    int g = blockIdx.x;
    int tid = threadIdx.x;
    size_t base = (size_t)g * 32 * F;
    for (int i = tid; i < 32 * F; i += blockDim.x) {
        float v = x[base + i];
        xl[i] = v;
        acb[i] = v;
    }
    if (tid < EPG) {
        es[tid] = src[g * EPG + tid] - g * NPG;
        ed[tid] = dst[g * EPG + tid] - g * NPG;
    }
    __syncthreads();
    if (tid < 64) {
        int e = tid;
        for (int c = 0; c < F; ++c)
            atomicAdd(&acb[ed[e] * F + c], xl[es[e] * F + c]);
    }
    __syncthreads();
    for (int i = tid; i < 32 * F; i += blockDim.x)
        out[base + i] = acb[i];
}

// ---------------------------------------------------------------------------
// Final: y[i] = elu(bn(u[i,:])) . w + b   (K = 64)
// ---------------------------------------------------------------------------
__global__ void final_dot(const float* __restrict__ u, const float* __restrict__ w,
                          const float* __restrict__ b, float* __restrict__ y,
                          const float* __restrict__ stats, float inv_sM)
{
    __shared__ float pmv[64], piv[64], sw[64];
    int tid = threadIdx.x;
    if (tid < 64) {
        float s = stats[tid], ss = stats[64 + tid];
        float mn = s * inv_sM;
        float vr = ss * inv_sM - mn * mn;
        pmv[tid] = mn;
        piv[tid] = rsqrtf(vr + BN_EPS);
        sw[tid] = w[tid];
    }
    __syncthreads();
    int i = blockIdx.x * blockDim.x + tid;
    if (i >= BGRAPH) return;
    float acc = 0.f;
    #pragma unroll
    for (int k = 0; k < 64; ++k) {
        float v = (u[(size_t)i * 64 + k] - pmv[k]) * piv[k];
        v = (v > 0.f) ? v : expm1f(v);
        acc += v * sw[k];
    }
    y[i] = acc + b[0];
}

// ---------------------------------------------------------------------------
// Host driver. ~149 MB workspace.
// ---------------------------------------------------------------------------
extern "C" void kernel_launch(void* const* d_in, const int* in_sizes, int n_in,
                              void* d_out, int out_size, void* d_ws, size_t ws_size,
                              hipStream_t stream)
{
    const float* cell   = (const float*)d_in[0];
    const float* drug_x = (const float*)d_in[1];
    const int*   eidx   = (const int*)d_in[2];
    const float* ce1w = (const float*)d_in[4];  const float* ce1b = (const float*)d_in[5];
    const float* ce2w = (const float*)d_in[6];  const float* ce2b = (const float*)d_in[7];
    const float* ce3w = (const float*)d_in[8];  const float* ce3b = (const float*)d_in[9];
    const float* g11w = (const float*)d_in[10]; const float* g11b = (const float*)d_in[11];
    const float* g12w = (const float*)d_in[12]; const float* g12b = (const float*)d_in[13];
    const float* g21w = (const float*)d_in[14]; const float* g21b = (const float*)d_in[15];
    const float* g22w = (const float*)d_in[16]; const float* g22b = (const float*)d_in[17];
    const float* d1w  = (const float*)d_in[18]; const float* d1b  = (const float*)d_in[19];
    const float* d2w  = (const float*)d_in[20]; const float* d2b  = (const float*)d_in[21];
    const float* f1w  = (const float*)d_in[22]; const float* f1b  = (const float*)d_in[23];
    const float* f2w  = (const float*)d_in[24]; const float* f2b  = (const float*)d_in[25];
    const float* f3w  = (const float*)d_in[26]; const float* f3b  = (const float*)d_in[27];

    const int* src = eidx;
    const int* dst = eidx + NEDGE;
    float* out = (float*)d_out;

    const float INV_N = 1.f / (float)NNODE;
    const float INV_B = 1.f / (float)BGRAPH;
    const int KBIG = 1 << 30;

    // ---- workspace layout ----
    float* ws   = (float*)d_ws;
    float* big  = ws;                                   // NNODE*128 floats
    float* aux  = ws + (size_t)NNODE * 128;             // NNODE*9 floats
    float* sb   = aux + (size_t)NNODE * 9;              // 10*1032 stats floats
    unsigned short* wtb = (unsigned short*)(sb + 10 * 1032);
    auto ST = [&](int i) { return sb + (size_t)i * 1032; };
    float* st_u1    = ST(0);
    float* st_u2rel = ST(1);
    float* st_u3    = ST(2);
    float* st_u4rel = ST(3);
    float* st_c1    = ST(4);
    float* st_c2    = ST(5);
    float* st_c3    = ST(6);
    float* st_d1    = ST(7);
    float* st_f1    = ST(8);
    float* st_f2    = ST(9);

    struct WDef { const float* w; int K; int N; };
    WDef wd[11] = {
        {ce1w, CELLD, 516}, {ce2w, 516, 256}, {ce3w, 256, 128},
        {g11w, 9, 128}, {g12w, 128, 128}, {g21w, 128, 128}, {g22w, 128, 128},
        {d1w, 128, 128}, {d2w, 128, 128}, {f1w, 256, 128}, {f2w, 128, 64}
    };
    TArgs ta;
    int off = 0;
    unsigned short* wt[11];
    for (int i = 0; i < 11; ++i) {
        wt[i] = wtb + off;
        ta.s[i] = TSeg{ wd[i].w, wt[i], wd[i].K, wd[i].N, off };
        off += wd[i].K * wd[i].N;
    }
    ta.total = off;

    // CSR arrays after weights (4-byte aligned: off is even-summed shorts; pad)
    int csr_off = (ta.total + 1) & ~1;
    int* row_start = (int*)(wtb + csr_off);
    int* col_idx   = row_start + (size_t)BGRAPH * 33;

    // small buffers inside `big` (used only after GIN branch is done with it)
    float* c1    = big;
    float* c2    = c1 + (size_t)BGRAPH * 516;
    float* c3u   = c2 + (size_t)BGRAPH * 256;
    float* dbuf  = c3u + (size_t)BGRAPH * 128;
    float* d2buf = dbuf + (size_t)BGRAPH * 128;
    float* f1o   = d2buf + (size_t)BGRAPH * 128;
    float* f2o   = f1o + (size_t)BGRAPH * 128;
    float* pbuf  = aux;   // reused once g11 consumed aux

    zero_buf<<<(10 * 1032 + 255) / 256, 256, 0, stream>>>(sb, 10 * 1032);
    transpose_w<<<(ta.total + 255) / 256, 256, 0, stream>>>(ta);
    csr_build<<<BGRAPH, 64, 0, stream>>>(src, dst, row_start, col_idx);

    // ================= GIN branch (in-place in `big`) ========================
    gin_agg9<<<BGRAPH, 128, 0, stream>>>(drug_x, src, dst, aux);
    // g11: K=9
    gemm_rA<1, 128><<<NNODE / 128, 256, 0, stream>>>(
        aux, nullptr, 9, 9, 9, KBIG, wt[3], g11b, big,
        nullptr, 0.f, 0, st_u1, 1, 0, nullptr);
    // g12: relu(bn(u1)) @ W, stats of relu(u2)
    gemm_rA<4, 128><<<NNODE / 128, 256, 0, stream>>>(
        big, nullptr, 128, 128, 128, KBIG, wt[4], g12b, big,
        st_u1, INV_N, 1, st_u2rel, 2, 0, nullptr);
    // GIN2 aggregation by gather: h = bn(relu(u2)); big <- h + agg(h)
    gin_gather<<<BGRAPH, 256, 0, stream>>>(
        big, row_start, col_idx, big, st_u2rel, INV_N);
    // g21: raw input, stats of u3
    gemm_rA<4, 128><<<NNODE / 128, 256, 0, stream>>>(
        big, nullptr, 128, 128, 128, KBIG, wt[5], g21b, big,
        nullptr, 0.f, 0, st_u3, 1, 0, nullptr);
    // g22: relu(bn(u3)) @ W; NO C write; stats of relu(u4); pool max(relu(u4))
    gemm_rA<4, 128><<<NNODE / 128, 256, 0, stream>>>(
        big, nullptr, 128, 128, 128, KBIG, wt[6], g22b, nullptr,
        st_u3, INV_N, 1, st_u4rel, 2, 0, pbuf);

    // ================= cell branch ===========================================
    gemm_mfma<128><<<dim3(BGRAPH / 128, 5), 256, 0, stream>>>(
        cell, wt[0], ce1b, c1, BGRAPH, CELLD, 516, nullptr, 0.f, 0, st_c1, 1, 0);
    gemm_mfma<128><<<dim3(BGRAPH / 128, 2), 256, 0, stream>>>(
        c1, wt[1], ce2b, c2, BGRAPH, 516, 256, st_c1, INV_B, 1, st_c2, 1, 0);
    gemm_rA<8, 128><<<BGRAPH / 128, 256, 0, stream>>>(
        c2, nullptr, 256, 256, 256, KBIG, wt[2], ce3b, c3u,
        st_c2, INV_B, 1, st_c3, 1, 0, nullptr);

    // ================= d branch ==============================================
    gemm_rA<4, 128><<<BGRAPH / 128, 256, 0, stream>>>(
        pbuf, nullptr, 128, 128, 128, KBIG, wt[7], d1b, dbuf,
        st_u4rel, INV_N, 3, st_d1, 1, 0, nullptr);
    gemm_rA<4, 128><<<BGRAPH / 128, 256, 0, stream>>>(
        dbuf, nullptr, 128, 128, 128, KBIG, wt[8], d2b, d2buf,
        st_d1, INV_B, 1, nullptr, 0, 1, nullptr);

    // ================= head ==================================================
    gemm_rA<8, 128><<<BGRAPH / 128, 256, 0, stream>>>(
        c3u, d2buf, 128, 256, 128, 128, wt[9], f1b, f1o,
        st_c3, INV_B, 1, st_f1, 1, 0, nullptr);
    gemm_rA<4, 64><<<BGRAPH / 128, 256, 0, stream>>>(
        f1o, nullptr, 128, 128, 128, KBIG, wt[10], f2b, f2o,
        st_f1, INV_B, 2, st_f2, 1, 0, nullptr);
    final_dot<<<BGRAPH / 256, 256, 0, stream>>>(f2o, f3w, f3b, out, st_f2, INV_B);
}

// Round 7
// 819.710 us; speedup vs baseline: 1.4613x; 1.1103x over previous
//
#include <hip/hip_runtime.h>
#include <hip/hip_bf16.h>
#include <math.h>

// Problem constants (from reference)
#define BGRAPH 8192
#define NPG 32
#define EPG 64
#define NNODE (BGRAPH * NPG)   // 262144
#define NEDGE (BGRAPH * EPG)   // 524288
#define CELLD 908
#define BN_EPS 1e-5f

typedef __attribute__((ext_vector_type(8))) short bf16x8;   // 8 bf16 = 4 VGPRs
typedef __attribute__((ext_vector_type(4))) float f32x4;
typedef __attribute__((ext_vector_type(4))) unsigned short us4;

__device__ __forceinline__ unsigned short f2bf(float f)
{
    unsigned int u = __float_as_uint(f);
    u = (u + 0x7FFFu + ((u >> 16) & 1u)) >> 16;   // RNE
    return (unsigned short)u;
}

// in_mode: 0=raw, 1=relu((x-m)*iv), 2=elu((x-m)*iv), 3=(relu(x)-m)*iv
__device__ __forceinline__ float apply_in(float v, int mode, float mn, float iv)
{
    if (mode == 1)      { v = (v - mn) * iv; v = fmaxf(v, 0.f); }
    else if (mode == 2) { v = (v - mn) * iv; v = (v > 0.f) ? v : expm1f(v); }
    else if (mode == 3) { v = fmaxf(v, 0.f); v = (v - mn) * iv; }
    return v;
}

// ---------------------------------------------------------------------------
// Merged setup: weight transpose+bf16 (blocks [0,tBlocks)), stats zero
// (next zBlocks), per-graph in-edge CSR (last 2048 blocks, 4 graphs each).
// ---------------------------------------------------------------------------
struct TSeg { const float* w; unsigned short* wt; int K; int N; int off; };
struct SetupArgs {
    TSeg s[11]; int tTotal; int tBlocks;
    float* zb; int zTotal; int zBlocks;
    const int* src; const int* dst; int* row_start; int* col_idx;
};

__global__ void setup_all(SetupArgs a)
{
    int b = blockIdx.x;
    int tid = threadIdx.x;
    if (b < a.tBlocks) {
        int i = b * 256 + tid;
        if (i < a.tTotal) {
            int j = 0;
            while (j < 10 && i >= a.s[j + 1].off) ++j;
            int idx = i - a.s[j].off;
            int K = a.s[j].K, N = a.s[j].N;
            int n = idx / K, k = idx - n * K;
            a.s[j].wt[idx] = f2bf(a.s[j].w[(size_t)k * N + n]);
        }
        return;
    }
    b -= a.tBlocks;
    if (b < a.zBlocks) {
        int i = b * 256 + tid;
        if (i < a.zTotal) a.zb[i] = 0.f;
        return;
    }
    b -= a.zBlocks;
    // CSR build: 4 graphs per block
    __shared__ int cnt[4][32], fill[4][32], rs[4][33];
    int gl = tid >> 6, e = tid & 63;
    int g = b * 4 + gl;
    if (e < 32) { cnt[gl][e] = 0; fill[gl][e] = 0; }
    __syncthreads();
    int s = a.src[g * EPG + e] - g * NPG;
    int d = a.dst[g * EPG + e] - g * NPG;
    atomicAdd(&cnt[gl][d], 1);
    __syncthreads();
    if (e == 0) {
        int acc = 0;
        for (int i = 0; i < 32; ++i) { rs[gl][i] = acc; acc += cnt[gl][i]; }
        rs[gl][32] = acc;
    }
    __syncthreads();
    int pos = rs[gl][d] + atomicAdd(&fill[gl][d], 1);
    a.col_idx[g * EPG + pos] = s;
    if (e < 33) a.row_start[g * 33 + e] = rs[gl][e];
}

// ---------------------------------------------------------------------------
// GIN aggregation by GATHER (F=128): out[n,c] = f(x)[n,c] + sum_{in(n)} ...
// f = bn(relu(.)). One graph per block, 256 threads, 16 KB LDS. In-place safe.
// ---------------------------------------------------------------------------
__global__ void gin_gather(const float* __restrict__ x,
                           const int* __restrict__ row_start,
                           const int* __restrict__ col_idx,
                           float* __restrict__ out,
                           const float* __restrict__ in_stats, float inv_sM)
{
    __shared__ float xl[32 * 128];
    __shared__ float pm[128], pv[128];
    __shared__ int rs[33], ci[64];
    int g = blockIdx.x;
    int tid = threadIdx.x;

    if (tid < 128) {
        float s = in_stats[tid], ss = in_stats[128 + tid];
        float mn = s * inv_sM;
        float vr = ss * inv_sM - mn * mn;
        pm[tid] = mn;
        pv[tid] = rsqrtf(vr + BN_EPS);
    } else if (tid < 161) {
        rs[tid - 128] = row_start[g * 33 + (tid - 128)];
    } else if (tid < 225) {
        ci[tid - 161] = col_idx[g * EPG + (tid - 161)];
    }
    __syncthreads();

    size_t base = (size_t)g * 32 * 128;
    for (int i = tid; i < 32 * 32; i += 256) {
        float4 f = *(const float4*)&x[base + i * 4];
        int c = (i & 31) * 4;
        float4 t;
        t.x = (fmaxf(f.x, 0.f) - pm[c])     * pv[c];
        t.y = (fmaxf(f.y, 0.f) - pm[c + 1]) * pv[c + 1];
        t.z = (fmaxf(f.z, 0.f) - pm[c + 2]) * pv[c + 2];
        t.w = (fmaxf(f.w, 0.f) - pm[c + 3]) * pv[c + 3];
        *(float4*)&xl[i * 4] = t;
    }
    __syncthreads();

    int c = tid & 127;
    int h = tid >> 7;
    #pragma unroll
    for (int i = 0; i < 16; ++i) {
        int n = h * 16 + i;
        float a = xl[n * 128 + c];
        int e0 = rs[n], e1 = rs[n + 1];
        for (int j = e0; j < e1; ++j)
            a += xl[ci[j] * 128 + c];
        out[base + n * 128 + c] = a;
    }
}

// ---------------------------------------------------------------------------
// Register-A MFMA GEMM. Tile MT x NT (MT in {64,128}), K <= KSTEPS*32,
// N == NT. W resident in LDS once. A loaded directly to regs, BN transform
// fused on load. Optional dual A source, skip-C, column stats, per-graph
// max-pool (MT=128 only). In-place safe. M must be a multiple of MT.
// ---------------------------------------------------------------------------
template<int MT, int KSTEPS, int NT>
__launch_bounds__(256)
__global__ void gemm_rA(const float* __restrict__ A, const float* __restrict__ A2,
                        int lda, int K, int stats_K, int ksplit,
                        const unsigned short* __restrict__ Wt,
                        const float* __restrict__ bias, float* __restrict__ C,
                        const float* __restrict__ in_stats, float inv_sM, int in_mode,
                        float* __restrict__ out_stats, int stats_mode, int out_act,
                        float* __restrict__ pool_out)
{
    constexpr int LSTRW = KSTEPS * 32 + 8;
    constexpr int NSUB = NT / 16;
    constexpr int MF = MT / 64;          // A-frags per wave
    __shared__ unsigned short Ws_l[NT * LSTRW];
    __shared__ float pm[KSTEPS * 32], pv[KSTEPS * 32];
    __shared__ float red[4][2][NT];

    int tid  = threadIdx.x;
    int wave = tid >> 6;
    int lane = tid & 63;
    int quad = lane >> 4;
    int l16  = lane & 15;
    int m0   = blockIdx.x * MT;

    const bool kvec = ((K & 3) == 0);
    for (int i = tid; i < NT * (KSTEPS * 8); i += 256) {
        int n = i / (KSTEPS * 8), g4 = i % (KSTEPS * 8);
        int k = g4 * 4;
        us4 w = (us4){0, 0, 0, 0};
        if (k < K) {
            const unsigned short* wp = Wt + (size_t)n * K + k;
            if (kvec) w = *(const us4*)wp;
            else {
                w.x = wp[0];
                if (k + 1 < K) w.y = wp[1];
                if (k + 2 < K) w.z = wp[2];
                if (k + 3 < K) w.w = wp[3];
            }
        }
        *(us4*)&Ws_l[n * LSTRW + k] = w;
    }
    if (in_mode) {
        for (int k = tid; k < KSTEPS * 32; k += 256) {
            float mn = 0.f, iv = 1.f;
            if (k < stats_K) {
                float s = in_stats[k], ss = in_stats[stats_K + k];
                mn = s * inv_sM;
                float vr = ss * inv_sM - mn * mn;
                iv = rsqrtf(vr + BN_EPS);
            }
            pm[k] = mn; pv[k] = iv;
        }
    }
    __syncthreads();

    bf16x8 afrag[MF][KSTEPS];
    #pragma unroll
    for (int mt = 0; mt < MF; ++mt) {
        int row = m0 + wave * (16 * MF) + mt * 16 + l16;
        const float* ap = A + (size_t)row * lda;
        #pragma unroll
        for (int ks = 0; ks < KSTEPS; ++ks) {
            int kb = ks * 32 + quad * 8;
            float v[8];
            if (kvec) {
                #pragma unroll
                for (int h = 0; h < 2; ++h) {
                    int k = kb + h * 4;
                    const float* p = (k >= ksplit) ? &A2[(size_t)row * 128 + (k - 128)]
                                                   : &ap[k];
                    float4 f = *(const float4*)p;
                    v[h * 4 + 0] = f.x; v[h * 4 + 1] = f.y;
                    v[h * 4 + 2] = f.z; v[h * 4 + 3] = f.w;
                }
            } else {
                #pragma unroll
                for (int j = 0; j < 8; ++j) {
                    int k = kb + j;
                    v[j] = (k < K) ? ap[k] : 0.f;
                }
            }
            if (in_mode) {
                #pragma unroll
                for (int j = 0; j < 8; ++j)
                    v[j] = apply_in(v[j], in_mode, pm[kb + j], pv[kb + j]);
            }
            union { bf16x8 b; unsigned short u[8]; } fr;
            #pragma unroll
            for (int j = 0; j < 8; ++j) fr.u[j] = f2bf(v[j]);
            afrag[mt][ks] = fr.b;
        }
    }

    f32x4 acc[MF][NSUB];
    #pragma unroll
    for (int i = 0; i < MF; ++i)
        #pragma unroll
        for (int j = 0; j < NSUB; ++j)
            acc[i][j] = (f32x4){0.f, 0.f, 0.f, 0.f};

    #pragma unroll
    for (int ks = 0; ks < KSTEPS; ++ks) {
        #pragma unroll
        for (int nt = 0; nt < NSUB; ++nt) {
            bf16x8 b = *(const bf16x8*)(const void*)&Ws_l[(nt * 16 + l16) * LSTRW + ks * 32 + quad * 8];
            #pragma unroll
            for (int mt = 0; mt < MF; ++mt)
                acc[mt][nt] = __builtin_amdgcn_mfma_f32_16x16x32_bf16(afrag[mt][ks], b, acc[mt][nt], 0, 0, 0);
        }
    }

    float ls[NSUB], lq[NSUB];
    #pragma unroll
    for (int nt = 0; nt < NSUB; ++nt) { ls[nt] = 0.f; lq[nt] = 0.f; }

    #pragma unroll
    for (int nt = 0; nt < NSUB; ++nt) {
        int col = nt * 16 + l16;
        float bv = bias[col];
        float mx = -INFINITY;
        #pragma unroll
        for (int mt = 0; mt < MF; ++mt) {
            int rbase = m0 + wave * (16 * MF) + mt * 16 + quad * 4;
            #pragma unroll
            for (int r = 0; r < 4; ++r) {
                float u = acc[mt][nt][r] + bv;
                if (C) {
                    float wv = out_act ? fmaxf(u, 0.f) : u;
                    C[(size_t)(rbase + r) * NT + col] = wv;
                }
                float ru = fmaxf(u, 0.f);
                if (stats_mode) {
                    float s = (stats_mode == 2) ? ru : u;
                    ls[nt] += s; lq[nt] += s * s;
                }
                if (MF == 2 && pool_out) mx = fmaxf(mx, ru);
            }
        }
        if (MF == 2 && pool_out) {
            mx = fmaxf(mx, __shfl_xor(mx, 16));
            mx = fmaxf(mx, __shfl_xor(mx, 32));
            if (quad == 0) {
                int graph = (m0 + wave * 32) >> 5;
                pool_out[(size_t)graph * NT + col] = mx;
            }
        }
    }

    if (stats_mode) {
        #pragma unroll
        for (int nt = 0; nt < NSUB; ++nt) {
            float s = ls[nt], q = lq[nt];
            s += __shfl_xor(s, 16); q += __shfl_xor(q, 16);
            s += __shfl_xor(s, 32); q += __shfl_xor(q, 32);
            if (quad == 0) { red[wave][0][nt * 16 + l16] = s; red[wave][1][nt * 16 + l16] = q; }
        }
        __syncthreads();
        if (tid < NT) {
            float s = red[0][0][tid] + red[1][0][tid] + red[2][0][tid] + red[3][0][tid];
            float q = red[0][1][tid] + red[1][1][tid] + red[2][1][tid] + red[3][1][tid];
            unsafeAtomicAdd(&out_stats[tid], s);
            unsafeAtomicAdd(&out_stats[NT + tid], q);
        }
    }
}

// ---------------------------------------------------------------------------
// Cell-branch GEMM (large K): tile 64 x NT, 4 waves x 16 rows, K-chunk 64.
// Writes raw u, accumulates stats of u. High block count for occupancy.
// ---------------------------------------------------------------------------
template<int NT>
__launch_bounds__(256)
__global__ void gemm_cell(const float* __restrict__ A, const unsigned short* __restrict__ Wt,
                          const float* __restrict__ bias, float* __restrict__ C,
                          int M, int K, int N,
                          const float* __restrict__ in_stats, float inv_sM, int in_mode,
                          float* __restrict__ out_stats)
{
    constexpr int NSUB = NT / 16;
    __shared__ unsigned short As_l[64 * 72];
    __shared__ unsigned short Ws_l[NT * 72];
    __shared__ float pm[916], pv[916];
    __shared__ float red[4][2][NT];

    int tid = threadIdx.x;
    int wave = tid >> 6;
    int lane = tid & 63;
    int quad = lane >> 4;
    int l16 = lane & 15;
    int m0 = blockIdx.x * 64, n0 = blockIdx.y * NT;

    if (in_mode) {
        for (int k = tid; k < K; k += 256) {
            float s = in_stats[k], ss = in_stats[K + k];
            float mn = s * inv_sM;
            float vr = ss * inv_sM - mn * mn;
            pm[k] = mn; pv[k] = rsqrtf(vr + BN_EPS);
        }
        __syncthreads();
    }

    f32x4 acc[NSUB];
    #pragma unroll
    for (int j = 0; j < NSUB; ++j) acc[j] = (f32x4){0.f, 0.f, 0.f, 0.f};

    for (int k0 = 0; k0 < K; k0 += 64) {
        // stage A: 64 rows x 16 us4 granules (K % 4 == 0 for all uses)
        for (int i = tid; i < 64 * 16; i += 256) {
            int row = i >> 4, f4 = i & 15;
            int k = k0 + f4 * 4;
            us4 w4 = (us4){0, 0, 0, 0};
            if (k < K) {
                float4 f = *(const float4*)&A[(size_t)(m0 + row) * K + k];
                if (in_mode) {
                    f.x = apply_in(f.x, in_mode, pm[k], pv[k]);
                    f.y = apply_in(f.y, in_mode, pm[k + 1], pv[k + 1]);
                    f.z = apply_in(f.z, in_mode, pm[k + 2], pv[k + 2]);
                    f.w = apply_in(f.w, in_mode, pm[k + 3], pv[k + 3]);
                }
                w4 = (us4){ f2bf(f.x), f2bf(f.y), f2bf(f.z), f2bf(f.w) };
            }
            *(us4*)&As_l[row * 72 + f4 * 4] = w4;
        }
        // stage W
        for (int i = tid; i < NT * 16; i += 256) {
            int nn = i >> 4, kt = i & 15;
            int k = k0 + kt * 4;
            int gn = n0 + nn;
            us4 w4 = (us4){0, 0, 0, 0};
            if (gn < N && k < K) w4 = *(const us4*)&Wt[(size_t)gn * K + k];
            *(us4*)&Ws_l[nn * 72 + kt * 4] = w4;
        }
        __syncthreads();
        int rowb = wave * 16;
        #pragma unroll
        for (int ks = 0; ks < 2; ++ks) {
            bf16x8 a = *(const bf16x8*)(const void*)&As_l[(rowb + l16) * 72 + ks * 32 + quad * 8];
            #pragma unroll
            for (int nt = 0; nt < NSUB; ++nt) {
                bf16x8 b = *(const bf16x8*)(const void*)&Ws_l[(nt * 16 + l16) * 72 + ks * 32 + quad * 8];
                acc[nt] = __builtin_amdgcn_mfma_f32_16x16x32_bf16(a, b, acc[nt], 0, 0, 0);
            }
        }
        __syncthreads();
    }

    float ls[NSUB], lq[NSUB];
    #pragma unroll
    for (int nt = 0; nt < NSUB; ++nt) { ls[nt] = 0.f; lq[nt] = 0.f; }

    #pragma unroll
    for (int nt = 0; nt < NSUB; ++nt) {
        int col = n0 + nt * 16 + l16;
        if (col < N) {
            float bv = bias[col];
            int rbase = m0 + wave * 16 + quad * 4;
            #pragma unroll
            for (int r = 0; r < 4; ++r) {
                float u = acc[nt][r] + bv;
                C[(size_t)(rbase + r) * N + col] = u;
                ls[nt] += u; lq[nt] += u * u;
            }
        }
    }

    #pragma unroll
    for (int nt = 0; nt < NSUB; ++nt) {
        float s = ls[nt], q = lq[nt];
        s += __shfl_xor(s, 16); q += __shfl_xor(q, 16);
        s += __shfl_xor(s, 32); q += __shfl_xor(q, 32);
        if (quad == 0) { red[wave][0][nt * 16 + l16] = s; red[wave][1][nt * 16 + l16] = q; }
    }
    __syncthreads();
    if (tid < NT) {
        int col = n0 + tid;
        if (col < N) {
            float s = red[0][0][tid] + red[1][0][tid] + red[2][0][tid] + red[3][0][tid];
            float q = red[0][1][tid] + red[1][1][tid] + red[2][1][tid] + red[3][1][tid];
            unsafeAtomicAdd(&out_stats[col], s);
            unsafeAtomicAdd(&out_stats[N + col], q);
        }
    }
}

// ---------------------------------------------------------------------------
// GIN conv-1 input aggregation (F=9): out = x + segment_sum(x[src], dst)
// ---------------------------------------------------------------------------
__global__ void gin_agg9(const float* __restrict__ x, const int* __restrict__ src,
                         const int* __restrict__ dst, float* __restrict__ out)
{
    const int F = 9;
    __shared__ float xl[32 * F];
    __shared__ float acb[32 * F];
    __shared__ int es[EPG], ed[EPG];
    int g = blockIdx.x;
    int tid = threadIdx.x;
    size_t base = (size_t)g * 32 * F;
    for (int i = tid; i < 32 * F; i += blockDim.x) {
        float v = x[base + i];
        xl[i] = v;
        acb[i] = v;
    }
    if (tid < EPG) {
        es[tid] = src[g * EPG + tid] - g * NPG;
        ed[tid] = dst[g * EPG + tid] - g * NPG;
    }
    __syncthreads();
    if (tid < 64) {
        int e = tid;
        for (int c = 0; c < F; ++c)
            atomicAdd(&acb[ed[e] * F + c], xl[es[e] * F + c]);
    }
    __syncthreads();
    for (int i = tid; i < 32 * F; i += blockDim.x)
        out[base + i] = acb[i];
}

// ---------------------------------------------------------------------------
// Final: y[i] = elu(bn(u[i,:])) . w + b   (K = 64)
// ---------------------------------------------------------------------------
__global__ void final_dot(const float* __restrict__ u, const float* __restrict__ w,
                          const float* __restrict__ b, float* __restrict__ y,
                          const float* __restrict__ stats, float inv_sM)
{
    __shared__ float pmv[64], piv[64], sw[64];
    int tid = threadIdx.x;
    if (tid < 64) {
        float s = stats[tid], ss = stats[64 + tid];
        float mn = s * inv_sM;
        float vr = ss * inv_sM - mn * mn;
        pmv[tid] = mn;
        piv[tid] = rsqrtf(vr + BN_EPS);
        sw[tid] = w[tid];
    }
    __syncthreads();
    int i = blockIdx.x * blockDim.x + tid;
    if (i >= BGRAPH) return;
    float acc = 0.f;
    #pragma unroll
    for (int k = 0; k < 64; ++k) {
        float v = (u[(size_t)i * 64 + k] - pmv[k]) * piv[k];
        v = (v > 0.f) ? v : expm1f(v);
        acc += v * sw[k];
    }
    y[i] = acc + b[0];
}

// ---------------------------------------------------------------------------
// Host driver. 14 launches, ~149 MB workspace.
// ---------------------------------------------------------------------------
extern "C" void kernel_launch(void* const* d_in, const int* in_sizes, int n_in,
                              void* d_out, int out_size, void* d_ws, size_t ws_size,
                              hipStream_t stream)
{
    const float* cell   = (const float*)d_in[0];
    const float* drug_x = (const float*)d_in[1];
    const int*   eidx   = (const int*)d_in[2];
    const float* ce1w = (const float*)d_in[4];  const float* ce1b = (const float*)d_in[5];
    const float* ce2w = (const float*)d_in[6];  const float* ce2b = (const float*)d_in[7];
    const float* ce3w = (const float*)d_in[8];  const float* ce3b = (const float*)d_in[9];
    const float* g11w = (const float*)d_in[10]; const float* g11b = (const float*)d_in[11];
    const float* g12w = (const float*)d_in[12]; const float* g12b = (const float*)d_in[13];
    const float* g21w = (const float*)d_in[14]; const float* g21b = (const float*)d_in[15];
    const float* g22w = (const float*)d_in[16]; const float* g22b = (const float*)d_in[17];
    const float* d1w  = (const float*)d_in[18]; const float* d1b  = (const float*)d_in[19];
    const float* d2w  = (const float*)d_in[20]; const float* d2b  = (const float*)d_in[21];
    const float* f1w  = (const float*)d_in[22]; const float* f1b  = (const float*)d_in[23];
    const float* f2w  = (const float*)d_in[24]; const float* f2b  = (const float*)d_in[25];
    const float* f3w  = (const float*)d_in[26]; const float* f3b  = (const float*)d_in[27];

    const int* src = eidx;
    const int* dst = eidx + NEDGE;
    float* out = (float*)d_out;

    const float INV_N = 1.f / (float)NNODE;
    const float INV_B = 1.f / (float)BGRAPH;
    const int KBIG = 1 << 30;

    // ---- workspace layout ----
    float* ws   = (float*)d_ws;
    float* big  = ws;                                   // NNODE*128 floats
    float* aux  = ws + (size_t)NNODE * 128;             // NNODE*9 floats
    float* sb   = aux + (size_t)NNODE * 9;              // 10*1032 stats floats
    unsigned short* wtb = (unsigned short*)(sb + 10 * 1032);
    auto ST = [&](int i) { return sb + (size_t)i * 1032; };
    float* st_u1    = ST(0);
    float* st_u2rel = ST(1);
    float* st_u3    = ST(2);
    float* st_u4rel = ST(3);
    float* st_c1    = ST(4);
    float* st_c2    = ST(5);
    float* st_c3    = ST(6);
    float* st_d1    = ST(7);
    float* st_f1    = ST(8);
    float* st_f2    = ST(9);

    struct WDef { const float* w; int K; int N; };
    WDef wd[11] = {
        {ce1w, CELLD, 516}, {ce2w, 516, 256}, {ce3w, 256, 128},
        {g11w, 9, 128}, {g12w, 128, 128}, {g21w, 128, 128}, {g22w, 128, 128},
        {d1w, 128, 128}, {d2w, 128, 128}, {f1w, 256, 128}, {f2w, 128, 64}
    };
    SetupArgs sa;
    int off = 0;
    unsigned short* wt[11];
    for (int i = 0; i < 11; ++i) {
        wt[i] = wtb + off;
        sa.s[i] = TSeg{ wd[i].w, wt[i], wd[i].K, wd[i].N, off };
        off += wd[i].K * wd[i].N;
    }
    sa.tTotal = off;
    sa.tBlocks = (off + 255) / 256;
    sa.zb = sb; sa.zTotal = 10 * 1032; sa.zBlocks = (10 * 1032 + 255) / 256;
    sa.src = src; sa.dst = dst;

    int csr_off = (off + 1) & ~1;
    int* row_start = (int*)(wtb + csr_off);
    int* col_idx   = row_start + (size_t)BGRAPH * 33;
    sa.row_start = row_start; sa.col_idx = col_idx;

    // small buffers inside `big` (used only after GIN branch is done with it)
    float* c1    = big;
    float* c2    = c1 + (size_t)BGRAPH * 516;
    float* c3u   = c2 + (size_t)BGRAPH * 256;
    float* dbuf  = c3u + (size_t)BGRAPH * 128;
    float* d2buf = dbuf + (size_t)BGRAPH * 128;
    float* f1o   = d2buf + (size_t)BGRAPH * 128;
    float* f2o   = f1o + (size_t)BGRAPH * 128;
    float* pbuf  = aux;   // reused once g11 consumed aux

    setup_all<<<sa.tBlocks + sa.zBlocks + BGRAPH / 4, 256, 0, stream>>>(sa);

    // ================= GIN branch (in-place in `big`) ========================
    gin_agg9<<<BGRAPH, 128, 0, stream>>>(drug_x, src, dst, aux);
    gemm_rA<128, 1, 128><<<NNODE / 128, 256, 0, stream>>>(
        aux, nullptr, 9, 9, 9, KBIG, wt[3], g11b, big,
        nullptr, 0.f, 0, st_u1, 1, 0, nullptr);
    gemm_rA<128, 4, 128><<<NNODE / 128, 256, 0, stream>>>(
        big, nullptr, 128, 128, 128, KBIG, wt[4], g12b, big,
        st_u1, INV_N, 1, st_u2rel, 2, 0, nullptr);
    gin_gather<<<BGRAPH, 256, 0, stream>>>(
        big, row_start, col_idx, big, st_u2rel, INV_N);
    gemm_rA<128, 4, 128><<<NNODE / 128, 256, 0, stream>>>(
        big, nullptr, 128, 128, 128, KBIG, wt[5], g21b, big,
        nullptr, 0.f, 0, st_u3, 1, 0, nullptr);
    gemm_rA<128, 4, 128><<<NNODE / 128, 256, 0, stream>>>(
        big, nullptr, 128, 128, 128, KBIG, wt[6], g22b, nullptr,
        st_u3, INV_N, 1, st_u4rel, 2, 0, pbuf);

    // ================= cell branch ===========================================
    gemm_cell<128><<<dim3(BGRAPH / 64, 5), 256, 0, stream>>>(
        cell, wt[0], ce1b, c1, BGRAPH, CELLD, 516, nullptr, 0.f, 0, st_c1);
    gemm_cell<64><<<dim3(BGRAPH / 64, 4), 256, 0, stream>>>(
        c1, wt[1], ce2b, c2, BGRAPH, 516, 256, st_c1, INV_B, 1, st_c2);
    gemm_rA<64, 8, 128><<<BGRAPH / 64, 256, 0, stream>>>(
        c2, nullptr, 256, 256, 256, KBIG, wt[2], ce3b, c3u,
        st_c2, INV_B, 1, st_c3, 1, 0, nullptr);

    // ================= d branch ==============================================
    gemm_rA<64, 4, 128><<<BGRAPH / 64, 256, 0, stream>>>(
        pbuf, nullptr, 128, 128, 128, KBIG, wt[7], d1b, dbuf,
        st_u4rel, INV_N, 3, st_d1, 1, 0, nullptr);
    gemm_rA<64, 4, 128><<<BGRAPH / 64, 256, 0, stream>>>(
        dbuf, nullptr, 128, 128, 128, KBIG, wt[8], d2b, d2buf,
        st_d1, INV_B, 1, nullptr, 0, 1, nullptr);

    // ================= head ==================================================
    gemm_rA<64, 8, 128><<<BGRAPH / 64, 256, 0, stream>>>(
        c3u, d2buf, 128, 256, 128, 128, wt[9], f1b, f1o,
        st_c3, INV_B, 1, st_f1, 1, 0, nullptr);
    gemm_rA<64, 4, 64><<<BGRAPH / 64, 256, 0, stream>>>(
        f1o, nullptr, 128, 128, 128, KBIG, wt[10], f2b, f2o,
        st_f1, INV_B, 2, st_f2, 1, 0, nullptr);
    final_dot<<<BGRAPH / 256, 256, 0, stream>>>(f2o, f3w, f3b, out, st_f2, INV_B);
}

// Round 8
// 817.956 us; speedup vs baseline: 1.4645x; 1.0021x over previous
//
#include <hip/hip_runtime.h>
#include <hip/hip_bf16.h>
#include <math.h>

// Problem constants (from reference)
#define BGRAPH 8192
#define NPG 32
#define EPG 64
#define NNODE (BGRAPH * NPG)   // 262144
#define NEDGE (BGRAPH * EPG)   // 524288
#define CELLD 908
#define BN_EPS 1e-5f

typedef __attribute__((ext_vector_type(8))) short bf16x8;   // 8 bf16 = 4 VGPRs
typedef __attribute__((ext_vector_type(4))) float f32x4;
typedef __attribute__((ext_vector_type(4))) unsigned short us4;

__device__ __forceinline__ unsigned short f2bf(float f)
{
    unsigned int u = __float_as_uint(f);
    u = (u + 0x7FFFu + ((u >> 16) & 1u)) >> 16;   // RNE
    return (unsigned short)u;
}

// in_mode: 0=raw, 1=relu((x-m)*iv), 2=elu((x-m)*iv), 3=(relu(x)-m)*iv
__device__ __forceinline__ float apply_in(float v, int mode, float mn, float iv)
{
    if (mode == 1)      { v = (v - mn) * iv; v = fmaxf(v, 0.f); }
    else if (mode == 2) { v = (v - mn) * iv; v = (v > 0.f) ? v : expm1f(v); }
    else if (mode == 3) { v = fmaxf(v, 0.f); v = (v - mn) * iv; }
    return v;
}

// ---------------------------------------------------------------------------
// Merged setup: weight transpose+bf16, stats zero, per-graph in-edge CSR.
// ---------------------------------------------------------------------------
struct TSeg { const float* w; unsigned short* wt; int K; int N; int off; };
struct SetupArgs {
    TSeg s[11]; int tTotal; int tBlocks;
    float* zb; int zTotal; int zBlocks;
    const int* src; const int* dst; int* row_start; int* col_idx;
};

__global__ void setup_all(SetupArgs a)
{
    int b = blockIdx.x;
    int tid = threadIdx.x;
    if (b < a.tBlocks) {
        int i = b * 256 + tid;
        if (i < a.tTotal) {
            int j = 0;
            while (j < 10 && i >= a.s[j + 1].off) ++j;
            int idx = i - a.s[j].off;
            int K = a.s[j].K, N = a.s[j].N;
            int n = idx / K, k = idx - n * K;
            a.s[j].wt[idx] = f2bf(a.s[j].w[(size_t)k * N + n]);
        }
        return;
    }
    b -= a.tBlocks;
    if (b < a.zBlocks) {
        int i = b * 256 + tid;
        if (i < a.zTotal) a.zb[i] = 0.f;
        return;
    }
    b -= a.zBlocks;
    // CSR build: 4 graphs per block
    __shared__ int cnt[4][32], fill[4][32], rs[4][33];
    int gl = tid >> 6, e = tid & 63;
    int g = b * 4 + gl;
    if (e < 32) { cnt[gl][e] = 0; fill[gl][e] = 0; }
    __syncthreads();
    int s = a.src[g * EPG + e] - g * NPG;
    int d = a.dst[g * EPG + e] - g * NPG;
    atomicAdd(&cnt[gl][d], 1);
    __syncthreads();
    if (e == 0) {
        int acc = 0;
        for (int i = 0; i < 32; ++i) { rs[gl][i] = acc; acc += cnt[gl][i]; }
        rs[gl][32] = acc;
    }
    __syncthreads();
    int pos = rs[gl][d] + atomicAdd(&fill[gl][d], 1);
    a.col_idx[g * EPG + pos] = s;
    if (e < 33) a.row_start[g * 33 + e] = rs[gl][e];
}

// ---------------------------------------------------------------------------
// Register-A MFMA GEMM. Tile MT x NT (MT in {64,128}), K <= KSTEPS*32,
// N == NT. A loads are issued BEFORE the W-stage barrier so their HBM latency
// overlaps staging. BN transform fused post-barrier. Optional dual A source,
// skip-C, column stats, per-graph max-pool (MT=128). In-place safe.
// ---------------------------------------------------------------------------
template<int MT, int KSTEPS, int NT>
__launch_bounds__(256)
__global__ void gemm_rA(const float* __restrict__ A, const float* __restrict__ A2,
                        int lda, int K, int stats_K, int ksplit,
                        const unsigned short* __restrict__ Wt,
                        const float* __restrict__ bias, float* __restrict__ C,
                        const float* __restrict__ in_stats, float inv_sM, int in_mode,
                        float* __restrict__ out_stats, int stats_mode, int out_act,
                        float* __restrict__ pool_out)
{
    constexpr int LSTRW = KSTEPS * 32 + 8;
    constexpr int NSUB = NT / 16;
    constexpr int MF = MT / 64;          // A-frags per wave
    __shared__ unsigned short Ws_l[NT * LSTRW];
    __shared__ float pm[KSTEPS * 32], pv[KSTEPS * 32];
    __shared__ float red[4][2][NT];

    int tid  = threadIdx.x;
    int wave = tid >> 6;
    int lane = tid & 63;
    int quad = lane >> 4;
    int l16  = lane & 15;
    int m0   = blockIdx.x * MT;

    const bool kvec = ((K & 3) == 0);

    // ---- issue A loads FIRST (latency overlaps W staging + barrier) ----
    float4 av[MF][KSTEPS][2];
    #pragma unroll
    for (int mt = 0; mt < MF; ++mt) {
        int row = m0 + wave * (16 * MF) + mt * 16 + l16;
        const float* ap = A + (size_t)row * lda;
        #pragma unroll
        for (int ks = 0; ks < KSTEPS; ++ks) {
            int kb = ks * 32 + quad * 8;
            if (kvec) {
                #pragma unroll
                for (int h = 0; h < 2; ++h) {
                    int k = kb + h * 4;
                    const float* p = (k >= ksplit) ? &A2[(size_t)row * 128 + (k - 128)]
                                                   : &ap[k];
                    av[mt][ks][h] = *(const float4*)p;
                }
            } else {
                float v[8];
                #pragma unroll
                for (int j = 0; j < 8; ++j) {
                    int k = kb + j;
                    v[j] = (k < K) ? ap[k] : 0.f;
                }
                av[mt][ks][0] = (float4){v[0], v[1], v[2], v[3]};
                av[mt][ks][1] = (float4){v[4], v[5], v[6], v[7]};
            }
        }
    }

    // ---- stage W (full K) and BN params ----
    for (int i = tid; i < NT * (KSTEPS * 8); i += 256) {
        int n = i / (KSTEPS * 8), g4 = i % (KSTEPS * 8);
        int k = g4 * 4;
        us4 w = (us4){0, 0, 0, 0};
        if (k < K) {
            const unsigned short* wp = Wt + (size_t)n * K + k;
            if (kvec) w = *(const us4*)wp;
            else {
                w.x = wp[0];
                if (k + 1 < K) w.y = wp[1];
                if (k + 2 < K) w.z = wp[2];
                if (k + 3 < K) w.w = wp[3];
            }
        }
        *(us4*)&Ws_l[n * LSTRW + k] = w;
    }
    if (in_mode) {
        for (int k = tid; k < KSTEPS * 32; k += 256) {
            float mn = 0.f, iv = 1.f;
            if (k < stats_K) {
                float s = in_stats[k], ss = in_stats[stats_K + k];
                mn = s * inv_sM;
                float vr = ss * inv_sM - mn * mn;
                iv = rsqrtf(vr + BN_EPS);
            }
            pm[k] = mn; pv[k] = iv;
        }
    }
    __syncthreads();

    // ---- transform + quantize A fragments ----
    bf16x8 afrag[MF][KSTEPS];
    #pragma unroll
    for (int mt = 0; mt < MF; ++mt) {
        #pragma unroll
        for (int ks = 0; ks < KSTEPS; ++ks) {
            int kb = ks * 32 + quad * 8;
            float v[8] = { av[mt][ks][0].x, av[mt][ks][0].y, av[mt][ks][0].z, av[mt][ks][0].w,
                           av[mt][ks][1].x, av[mt][ks][1].y, av[mt][ks][1].z, av[mt][ks][1].w };
            if (in_mode) {
                #pragma unroll
                for (int j = 0; j < 8; ++j)
                    v[j] = apply_in(v[j], in_mode, pm[kb + j], pv[kb + j]);
            }
            union { bf16x8 b; unsigned short u[8]; } fr;
            #pragma unroll
            for (int j = 0; j < 8; ++j) fr.u[j] = f2bf(v[j]);
            afrag[mt][ks] = fr.b;
        }
    }

    f32x4 acc[MF][NSUB];
    #pragma unroll
    for (int i = 0; i < MF; ++i)
        #pragma unroll
        for (int j = 0; j < NSUB; ++j)
            acc[i][j] = (f32x4){0.f, 0.f, 0.f, 0.f};

    #pragma unroll
    for (int ks = 0; ks < KSTEPS; ++ks) {
        #pragma unroll
        for (int nt = 0; nt < NSUB; ++nt) {
            bf16x8 b = *(const bf16x8*)(const void*)&Ws_l[(nt * 16 + l16) * LSTRW + ks * 32 + quad * 8];
            #pragma unroll
            for (int mt = 0; mt < MF; ++mt)
                acc[mt][nt] = __builtin_amdgcn_mfma_f32_16x16x32_bf16(afrag[mt][ks], b, acc[mt][nt], 0, 0, 0);
        }
    }

    float ls[NSUB], lq[NSUB];
    #pragma unroll
    for (int nt = 0; nt < NSUB; ++nt) { ls[nt] = 0.f; lq[nt] = 0.f; }

    #pragma unroll
    for (int nt = 0; nt < NSUB; ++nt) {
        int col = nt * 16 + l16;
        float bv = bias[col];
        float mx = -INFINITY;
        #pragma unroll
        for (int mt = 0; mt < MF; ++mt) {
            int rbase = m0 + wave * (16 * MF) + mt * 16 + quad * 4;
            #pragma unroll
            for (int r = 0; r < 4; ++r) {
                float u = acc[mt][nt][r] + bv;
                if (C) {
                    float wv = out_act ? fmaxf(u, 0.f) : u;
                    C[(size_t)(rbase + r) * NT + col] = wv;
                }
                float ru = fmaxf(u, 0.f);
                if (stats_mode) {
                    float s = (stats_mode == 2) ? ru : u;
                    ls[nt] += s; lq[nt] += s * s;
                }
                if (MF == 2 && pool_out) mx = fmaxf(mx, ru);
            }
        }
        if (MF == 2 && pool_out) {
            mx = fmaxf(mx, __shfl_xor(mx, 16));
            mx = fmaxf(mx, __shfl_xor(mx, 32));
            if (quad == 0) {
                int graph = (m0 + wave * 32) >> 5;
                pool_out[(size_t)graph * NT + col] = mx;
            }
        }
    }

    if (stats_mode) {
        #pragma unroll
        for (int nt = 0; nt < NSUB; ++nt) {
            float s = ls[nt], q = lq[nt];
            s += __shfl_xor(s, 16); q += __shfl_xor(q, 16);
            s += __shfl_xor(s, 32); q += __shfl_xor(q, 32);
            if (quad == 0) { red[wave][0][nt * 16 + l16] = s; red[wave][1][nt * 16 + l16] = q; }
        }
        __syncthreads();
        if (tid < NT) {
            float s = red[0][0][tid] + red[1][0][tid] + red[2][0][tid] + red[3][0][tid];
            float q = red[0][1][tid] + red[1][1][tid] + red[2][1][tid] + red[3][1][tid];
            unsafeAtomicAdd(&out_stats[tid], s);
            unsafeAtomicAdd(&out_stats[NT + tid], q);
        }
    }
}

// ---------------------------------------------------------------------------
// Fused GIN-2: block = 128 rows = 4 whole graphs. Per 64-col chunk: stage
// h = bn(relu(u2)) in fp32 LDS, GATHER-aggregate via CSR (no atomics),
// quantize frags, MFMA. C = (h+agg) @ W + bias, stats of u. In-place safe.
// K = N = 128. ~76 KB LDS -> 2 blocks/CU.
// ---------------------------------------------------------------------------
__launch_bounds__(256)
__global__ void gemm_g21(const float* __restrict__ A,
                         const unsigned short* __restrict__ Wt,
                         const float* __restrict__ bias, float* __restrict__ C,
                         const int* __restrict__ row_start, const int* __restrict__ col_idx,
                         const float* __restrict__ in_stats, float inv_sM,
                         float* __restrict__ out_stats)
{
    __shared__ unsigned short Ws_l[128 * 136];   // 34816 B
    __shared__ float xl[128 * 68];               // 34816 B (64 cols + 4 pad)
    __shared__ float pm[128], pv[128];
    __shared__ int rs[132], ci[256];
    __shared__ float red[4][2][128];

    int tid  = threadIdx.x;
    int wave = tid >> 6;
    int lane = tid & 63;
    int quad = lane >> 4;
    int l16  = lane & 15;
    int m0   = blockIdx.x * 128;
    int g0   = m0 >> 5;                // first of 4 graphs

    // stage W (full K=128)
    for (int i = tid; i < 128 * 32; i += 256) {
        int n = i >> 5, k = (i & 31) * 4;
        *(us4*)&Ws_l[n * 136 + k] = *(const us4*)&Wt[(size_t)n * 128 + k];
    }
    if (tid < 128) {
        float s = in_stats[tid], ss = in_stats[128 + tid];
        float mn = s * inv_sM;
        float vr = ss * inv_sM - mn * mn;
        pm[tid] = mn;
        pv[tid] = rsqrtf(vr + BN_EPS);
    }
    if (tid < 132) {
        int gl = tid / 33, idx = tid - gl * 33;
        rs[tid] = row_start[(g0 + gl) * 33 + idx];
    }
    {
        int gl = tid >> 6, e = tid & 63;
        ci[tid] = col_idx[(g0 + gl) * EPG + e] + gl * 32;   // block-local row
    }
    __syncthreads();

    f32x4 acc[2][8];
    #pragma unroll
    for (int i = 0; i < 2; ++i)
        #pragma unroll
        for (int j = 0; j < 8; ++j)
            acc[i][j] = (f32x4){0.f, 0.f, 0.f, 0.f};

    for (int ch = 0; ch < 2; ++ch) {
        // stage transformed 64-col chunk (fp32)
        for (int i = tid; i < 128 * 16; i += 256) {
            int row = i >> 4, f4 = (i & 15) * 4;
            int k = ch * 64 + f4;
            float4 f = *(const float4*)&A[(size_t)(m0 + row) * 128 + k];
            float4 t;
            t.x = (fmaxf(f.x, 0.f) - pm[k])     * pv[k];
            t.y = (fmaxf(f.y, 0.f) - pm[k + 1]) * pv[k + 1];
            t.z = (fmaxf(f.z, 0.f) - pm[k + 2]) * pv[k + 2];
            t.w = (fmaxf(f.w, 0.f) - pm[k + 3]) * pv[k + 3];
            *(float4*)&xl[row * 68 + f4] = t;
        }
        __syncthreads();

        #pragma unroll
        for (int ks2 = 0; ks2 < 2; ++ks2) {
            int kb = ks2 * 32 + quad * 8;     // offset within chunk [0,64)
            bf16x8 af[2];
            #pragma unroll
            for (int mt = 0; mt < 2; ++mt) {
                int rowl = wave * 32 + mt * 16 + l16;   // block-local row
                int gl = rowl >> 5, nloc = rowl & 31;
                int e0 = rs[gl * 33 + nloc], e1 = rs[gl * 33 + nloc + 1];
                float v[8];
                #pragma unroll
                for (int j = 0; j < 8; ++j) v[j] = xl[rowl * 68 + kb + j];
                for (int e = e0; e < e1; ++e) {
                    int sr = ci[(gl << 6) + e];
                    #pragma unroll
                    for (int j = 0; j < 8; ++j) v[j] += xl[sr * 68 + kb + j];
                }
                union { bf16x8 b; unsigned short u[8]; } fr;
                #pragma unroll
                for (int j = 0; j < 8; ++j) fr.u[j] = f2bf(v[j]);
                af[mt] = fr.b;
            }
            int kg = ch * 64 + kb;
            #pragma unroll
            for (int nt = 0; nt < 8; ++nt) {
                bf16x8 b = *(const bf16x8*)(const void*)&Ws_l[(nt * 16 + l16) * 136 + kg];
                acc[0][nt] = __builtin_amdgcn_mfma_f32_16x16x32_bf16(af[0], b, acc[0][nt], 0, 0, 0);
                acc[1][nt] = __builtin_amdgcn_mfma_f32_16x16x32_bf16(af[1], b, acc[1][nt], 0, 0, 0);
            }
        }
        __syncthreads();   // protect xl before restage
    }

    // epilogue: write u3, stats of u
    float ls[8], lq[8];
    #pragma unroll
    for (int nt = 0; nt < 8; ++nt) { ls[nt] = 0.f; lq[nt] = 0.f; }
    #pragma unroll
    for (int nt = 0; nt < 8; ++nt) {
        int col = nt * 16 + l16;
        float bv = bias[col];
        #pragma unroll
        for (int mt = 0; mt < 2; ++mt) {
            int rbase = m0 + wave * 32 + mt * 16 + quad * 4;
            #pragma unroll
            for (int r = 0; r < 4; ++r) {
                float u = acc[mt][nt][r] + bv;
                C[(size_t)(rbase + r) * 128 + col] = u;
                ls[nt] += u; lq[nt] += u * u;
            }
        }
    }
    #pragma unroll
    for (int nt = 0; nt < 8; ++nt) {
        float s = ls[nt], q = lq[nt];
        s += __shfl_xor(s, 16); q += __shfl_xor(q, 16);
        s += __shfl_xor(s, 32); q += __shfl_xor(q, 32);
        if (quad == 0) { red[wave][0][nt * 16 + l16] = s; red[wave][1][nt * 16 + l16] = q; }
    }
    __syncthreads();
    if (tid < 128) {
        float s = red[0][0][tid] + red[1][0][tid] + red[2][0][tid] + red[3][0][tid];
        float q = red[0][1][tid] + red[1][1][tid] + red[2][1][tid] + red[3][1][tid];
        unsafeAtomicAdd(&out_stats[tid], s);
        unsafeAtomicAdd(&out_stats[128 + tid], q);
    }
}

// ---------------------------------------------------------------------------
// Cell-branch GEMM (large K): tile 64 x NT, 4 waves x 16 rows, K-chunk 64.
// ---------------------------------------------------------------------------
template<int NT>
__launch_bounds__(256)
__global__ void gemm_cell(const float* __restrict__ A, const unsigned short* __restrict__ Wt,
                          const float* __restrict__ bias, float* __restrict__ C,
                          int M, int K, int N,
                          const float* __restrict__ in_stats, float inv_sM, int in_mode,
                          float* __restrict__ out_stats)
{
    constexpr int NSUB = NT / 16;
    __shared__ unsigned short As_l[64 * 72];
    __shared__ unsigned short Ws_l[NT * 72];
    __shared__ float pm[916], pv[916];
    __shared__ float red[4][2][NT];

    int tid = threadIdx.x;
    int wave = tid >> 6;
    int lane = tid & 63;
    int quad = lane >> 4;
    int l16 = lane & 15;
    int m0 = blockIdx.x * 64, n0 = blockIdx.y * NT;

    if (in_mode) {
        for (int k = tid; k < K; k += 256) {
            float s = in_stats[k], ss = in_stats[K + k];
            float mn = s * inv_sM;
            float vr = ss * inv_sM - mn * mn;
            pm[k] = mn; pv[k] = rsqrtf(vr + BN_EPS);
        }
        __syncthreads();
    }

    f32x4 acc[NSUB];
    #pragma unroll
    for (int j = 0; j < NSUB; ++j) acc[j] = (f32x4){0.f, 0.f, 0.f, 0.f};

    for (int k0 = 0; k0 < K; k0 += 64) {
        for (int i = tid; i < 64 * 16; i += 256) {
            int row = i >> 4, f4 = i & 15;
            int k = k0 + f4 * 4;
            us4 w4 = (us4){0, 0, 0, 0};
            if (k < K) {
                float4 f = *(const float4*)&A[(size_t)(m0 + row) * K + k];
                if (in_mode) {
                    f.x = apply_in(f.x, in_mode, pm[k], pv[k]);
                    f.y = apply_in(f.y, in_mode, pm[k + 1], pv[k + 1]);
                    f.z = apply_in(f.z, in_mode, pm[k + 2], pv[k + 2]);
                    f.w = apply_in(f.w, in_mode, pm[k + 3], pv[k + 3]);
                }
                w4 = (us4){ f2bf(f.x), f2bf(f.y), f2bf(f.z), f2bf(f.w) };
            }
            *(us4*)&As_l[row * 72 + f4 * 4] = w4;
        }
        for (int i = tid; i < NT * 16; i += 256) {
            int nn = i >> 4, kt = i & 15;
            int k = k0 + kt * 4;
            int gn = n0 + nn;
            us4 w4 = (us4){0, 0, 0, 0};
            if (gn < N && k < K) w4 = *(const us4*)&Wt[(size_t)gn * K + k];
            *(us4*)&Ws_l[nn * 72 + kt * 4] = w4;
        }
        __syncthreads();
        int rowb = wave * 16;
        #pragma unroll
        for (int ks = 0; ks < 2; ++ks) {
            bf16x8 a = *(const bf16x8*)(const void*)&As_l[(rowb + l16) * 72 + ks * 32 + quad * 8];
            #pragma unroll
            for (int nt = 0; nt < NSUB; ++nt) {
                bf16x8 b = *(const bf16x8*)(const void*)&Ws_l[(nt * 16 + l16) * 72 + ks * 32 + quad * 8];
                acc[nt] = __builtin_amdgcn_mfma_f32_16x16x32_bf16(a, b, acc[nt], 0, 0, 0);
            }
        }
        __syncthreads();
    }

    float ls[NSUB], lq[NSUB];
    #pragma unroll
    for (int nt = 0; nt < NSUB; ++nt) { ls[nt] = 0.f; lq[nt] = 0.f; }

    #pragma unroll
    for (int nt = 0; nt < NSUB; ++nt) {
        int col = n0 + nt * 16 + l16;
        if (col < N) {
            float bv = bias[col];
            int rbase = m0 + wave * 16 + quad * 4;
            #pragma unroll
            for (int r = 0; r < 4; ++r) {
                float u = acc[nt][r] + bv;
                C[(size_t)(rbase + r) * N + col] = u;
                ls[nt] += u; lq[nt] += u * u;
            }
        }
    }

    #pragma unroll
    for (int nt = 0; nt < NSUB; ++nt) {
        float s = ls[nt], q = lq[nt];
        s += __shfl_xor(s, 16); q += __shfl_xor(q, 16);
        s += __shfl_xor(s, 32); q += __shfl_xor(q, 32);
        if (quad == 0) { red[wave][0][nt * 16 + l16] = s; red[wave][1][nt * 16 + l16] = q; }
    }
    __syncthreads();
    if (tid < NT) {
        int col = n0 + tid;
        if (col < N) {
            float s = red[0][0][tid] + red[1][0][tid] + red[2][0][tid] + red[3][0][tid];
            float q = red[0][1][tid] + red[1][1][tid] + red[2][1][tid] + red[3][1][tid];
            unsafeAtomicAdd(&out_stats[col], s);
            unsafeAtomicAdd(&out_stats[N + col], q);
        }
    }
}

// ---------------------------------------------------------------------------
// GIN conv-1 input aggregation (F=9): out = x + segment_sum(x[src], dst)
// ---------------------------------------------------------------------------
__global__ void gin_agg9(const float* __restrict__ x, const int* __restrict__ src,
                         const int* __restrict__ dst, float* __restrict__ out)
{
    const int F = 9;
    __shared__ float xl[32 * F];
    __shared__ float acb[32 * F];
    __shared__ int es[EPG], ed[EPG];
    int g = blockIdx.x;
    int tid = threadIdx.x;
    size_t base = (size_t)g * 32 * F;
    for (int i = tid; i < 32 * F; i += blockDim.x) {
        float v = x[base + i];
        xl[i] = v;
        acb[i] = v;
    }
    if (tid < EPG) {
        es[tid] = src[g * EPG + tid] - g * NPG;
        ed[tid] = dst[g * EPG + tid] - g * NPG;
    }
    __syncthreads();
    if (tid < 64) {
        int e = tid;
        for (int c = 0; c < F; ++c)
            atomicAdd(&acb[ed[e] * F + c], xl[es[e] * F + c]);
    }
    __syncthreads();
    for (int i = tid; i < 32 * F; i += blockDim.x)
        out[base + i] = acb[i];
}

// ---------------------------------------------------------------------------
// Final: y[i] = elu(bn(u[i,:])) . w + b   (K = 64)
// ---------------------------------------------------------------------------
__global__ void final_dot(const float* __restrict__ u, const float* __restrict__ w,
                          const float* __restrict__ b, float* __restrict__ y,
                          const float* __restrict__ stats, float inv_sM)
{
    __shared__ float pmv[64], piv[64], sw[64];
    int tid = threadIdx.x;
    if (tid < 64) {
        float s = stats[tid], ss = stats[64 + tid];
        float mn = s * inv_sM;
        float vr = ss * inv_sM - mn * mn;
        pmv[tid] = mn;
        piv[tid] = rsqrtf(vr + BN_EPS);
        sw[tid] = w[tid];
    }
    __syncthreads();
    int i = blockIdx.x * blockDim.x + tid;
    if (i >= BGRAPH) return;
    float acc = 0.f;
    #pragma unroll
    for (int k = 0; k < 64; ++k) {
        float v = (u[(size_t)i * 64 + k] - pmv[k]) * piv[k];
        v = (v > 0.f) ? v : expm1f(v);
        acc += v * sw[k];
    }
    y[i] = acc + b[0];
}

// ---------------------------------------------------------------------------
// Host driver. 13 launches, ~149 MB workspace.
// ---------------------------------------------------------------------------
extern "C" void kernel_launch(void* const* d_in, const int* in_sizes, int n_in,
                              void* d_out, int out_size, void* d_ws, size_t ws_size,
                              hipStream_t stream)
{
    const float* cell   = (const float*)d_in[0];
    const float* drug_x = (const float*)d_in[1];
    const int*   eidx   = (const int*)d_in[2];
    const float* ce1w = (const float*)d_in[4];  const float* ce1b = (const float*)d_in[5];
    const float* ce2w = (const float*)d_in[6];  const float* ce2b = (const float*)d_in[7];
    const float* ce3w = (const float*)d_in[8];  const float* ce3b = (const float*)d_in[9];
    const float* g11w = (const float*)d_in[10]; const float* g11b = (const float*)d_in[11];
    const float* g12w = (const float*)d_in[12]; const float* g12b = (const float*)d_in[13];
    const float* g21w = (const float*)d_in[14]; const float* g21b = (const float*)d_in[15];
    const float* g22w = (const float*)d_in[16]; const float* g22b = (const float*)d_in[17];
    const float* d1w  = (const float*)d_in[18]; const float* d1b  = (const float*)d_in[19];
    const float* d2w  = (const float*)d_in[20]; const float* d2b  = (const float*)d_in[21];
    const float* f1w  = (const float*)d_in[22]; const float* f1b  = (const float*)d_in[23];
    const float* f2w  = (const float*)d_in[24]; const float* f2b  = (const float*)d_in[25];
    const float* f3w  = (const float*)d_in[26]; const float* f3b  = (const float*)d_in[27];

    const int* src = eidx;
    const int* dst = eidx + NEDGE;
    float* out = (float*)d_out;

    const float INV_N = 1.f / (float)NNODE;
    const float INV_B = 1.f / (float)BGRAPH;
    const int KBIG = 1 << 30;

    // ---- workspace layout ----
    float* ws   = (float*)d_ws;
    float* big  = ws;                                   // NNODE*128 floats
    float* aux  = ws + (size_t)NNODE * 128;             // NNODE*9 floats
    float* sb   = aux + (size_t)NNODE * 9;              // 10*1032 stats floats
    unsigned short* wtb = (unsigned short*)(sb + 10 * 1032);
    auto ST = [&](int i) { return sb + (size_t)i * 1032; };
    float* st_u1    = ST(0);
    float* st_u2rel = ST(1);
    float* st_u3    = ST(2);
    float* st_u4rel = ST(3);
    float* st_c1    = ST(4);
    float* st_c2    = ST(5);
    float* st_c3    = ST(6);
    float* st_d1    = ST(7);
    float* st_f1    = ST(8);
    float* st_f2    = ST(9);

    struct WDef { const float* w; int K; int N; };
    WDef wd[11] = {
        {ce1w, CELLD, 516}, {ce2w, 516, 256}, {ce3w, 256, 128},
        {g11w, 9, 128}, {g12w, 128, 128}, {g21w, 128, 128}, {g22w, 128, 128},
        {d1w, 128, 128}, {d2w, 128, 128}, {f1w, 256, 128}, {f2w, 128, 64}
    };
    SetupArgs sa;
    int off = 0;
    unsigned short* wt[11];
    for (int i = 0; i < 11; ++i) {
        wt[i] = wtb + off;
        sa.s[i] = TSeg{ wd[i].w, wt[i], wd[i].K, wd[i].N, off };
        off += wd[i].K * wd[i].N;
    }
    sa.tTotal = off;
    sa.tBlocks = (off + 255) / 256;
    sa.zb = sb; sa.zTotal = 10 * 1032; sa.zBlocks = (10 * 1032 + 255) / 256;
    sa.src = src; sa.dst = dst;

    int csr_off = (off + 1) & ~1;
    int* row_start = (int*)(wtb + csr_off);
    int* col_idx   = row_start + (size_t)BGRAPH * 33;
    sa.row_start = row_start; sa.col_idx = col_idx;

    // small buffers inside `big` (used only after GIN branch is done with it)
    float* c1    = big;
    float* c2    = c1 + (size_t)BGRAPH * 516;
    float* c3u   = c2 + (size_t)BGRAPH * 256;
    float* dbuf  = c3u + (size_t)BGRAPH * 128;
    float* d2buf = dbuf + (size_t)BGRAPH * 128;
    float* f1o   = d2buf + (size_t)BGRAPH * 128;
    float* f2o   = f1o + (size_t)BGRAPH * 128;
    float* pbuf  = aux;   // reused once g11 consumed aux

    setup_all<<<sa.tBlocks + sa.zBlocks + BGRAPH / 4, 256, 0, stream>>>(sa);

    // ================= GIN branch (in-place in `big`) ========================
    gin_agg9<<<BGRAPH, 128, 0, stream>>>(drug_x, src, dst, aux);
    gemm_rA<128, 1, 128><<<NNODE / 128, 256, 0, stream>>>(
        aux, nullptr, 9, 9, 9, KBIG, wt[3], g11b, big,
        nullptr, 0.f, 0, st_u1, 1, 0, nullptr);
    gemm_rA<128, 4, 128><<<NNODE / 128, 256, 0, stream>>>(
        big, nullptr, 128, 128, 128, KBIG, wt[4], g12b, big,
        st_u1, INV_N, 1, st_u2rel, 2, 0, nullptr);
    // g21 with fused gather-aggregation (h = bn(relu(u2)); u3 = (h+agg)@W)
    gemm_g21<<<NNODE / 128, 256, 0, stream>>>(
        big, wt[5], g21b, big, row_start, col_idx, st_u2rel, INV_N, st_u3);
    gemm_rA<128, 4, 128><<<NNODE / 128, 256, 0, stream>>>(
        big, nullptr, 128, 128, 128, KBIG, wt[6], g22b, nullptr,
        st_u3, INV_N, 1, st_u4rel, 2, 0, pbuf);

    // ================= cell branch ===========================================
    gemm_cell<128><<<dim3(BGRAPH / 64, 5), 256, 0, stream>>>(
        cell, wt[0], ce1b, c1, BGRAPH, CELLD, 516, nullptr, 0.f, 0, st_c1);
    gemm_cell<64><<<dim3(BGRAPH / 64, 4), 256, 0, stream>>>(
        c1, wt[1], ce2b, c2, BGRAPH, 516, 256, st_c1, INV_B, 1, st_c2);
    gemm_rA<64, 8, 128><<<BGRAPH / 64, 256, 0, stream>>>(
        c2, nullptr, 256, 256, 256, KBIG, wt[2], ce3b, c3u,
        st_c2, INV_B, 1, st_c3, 1, 0, nullptr);

    // ================= d branch ==============================================
    gemm_rA<64, 4, 128><<<BGRAPH / 64, 256, 0, stream>>>(
        pbuf, nullptr, 128, 128, 128, KBIG, wt[7], d1b, dbuf,
        st_u4rel, INV_N, 3, st_d1, 1, 0, nullptr);
    gemm_rA<64, 4, 128><<<BGRAPH / 64, 256, 0, stream>>>(
        dbuf, nullptr, 128, 128, 128, KBIG, wt[8], d2b, d2buf,
        st_d1, INV_B, 1, nullptr, 0, 1, nullptr);

    // ================= head ==================================================
    gemm_rA<64, 8, 128><<<BGRAPH / 64, 256, 0, stream>>>(
        c3u, d2buf, 128, 256, 128, 128, wt[9], f1b, f1o,
        st_c3, INV_B, 1, st_f1, 1, 0, nullptr);
    gemm_rA<64, 4, 64><<<BGRAPH / 64, 256, 0, stream>>>(
        f1o, nullptr, 128, 128, 128, KBIG, wt[10], f2b, f2o,
        st_f1, INV_B, 2, st_f2, 1, 0, nullptr);
    final_dot<<<BGRAPH / 256, 256, 0, stream>>>(f2o, f3w, f3b, out, st_f2, INV_B);
}

// Round 9
// 803.849 us; speedup vs baseline: 1.4902x; 1.0175x over previous
//
#include <hip/hip_runtime.h>
#include <hip/hip_bf16.h>
#include <math.h>

// Problem constants (from reference)
#define BGRAPH 8192
#define NPG 32
#define EPG 64
#define NNODE (BGRAPH * NPG)   // 262144
#define NEDGE (BGRAPH * EPG)   // 524288
#define CELLD 908
#define BN_EPS 1e-5f

typedef __attribute__((ext_vector_type(8))) short bf16x8;   // 8 bf16 = 4 VGPRs
typedef __attribute__((ext_vector_type(4))) float f32x4;
typedef __attribute__((ext_vector_type(4))) unsigned short us4;

__device__ __forceinline__ unsigned short f2bf(float f)
{
    unsigned int u = __float_as_uint(f);
    u = (u + 0x7FFFu + ((u >> 16) & 1u)) >> 16;   // RNE
    return (unsigned short)u;
}

// in_mode: 0=raw, 1=relu((x-m)*iv), 2=elu((x-m)*iv), 3=(relu(x)-m)*iv
__device__ __forceinline__ float apply_in(float v, int mode, float mn, float iv)
{
    if (mode == 1)      { v = (v - mn) * iv; v = fmaxf(v, 0.f); }
    else if (mode == 2) { v = (v - mn) * iv; v = (v > 0.f) ? v : expm1f(v); }
    else if (mode == 3) { v = fmaxf(v, 0.f); v = (v - mn) * iv; }
    return v;
}

// ---------------------------------------------------------------------------
// Merged setup: weight transpose+bf16, stats zero, per-graph in-edge CSR.
// ---------------------------------------------------------------------------
struct TSeg { const float* w; unsigned short* wt; int K; int N; int off; };
struct SetupArgs {
    TSeg s[11]; int tTotal; int tBlocks;
    float* zb; int zTotal; int zBlocks;
    const int* src; const int* dst; int* row_start; int* col_idx;
};

__global__ void setup_all(SetupArgs a)
{
    int b = blockIdx.x;
    int tid = threadIdx.x;
    if (b < a.tBlocks) {
        int i = b * 256 + tid;
        if (i < a.tTotal) {
            int j = 0;
            while (j < 10 && i >= a.s[j + 1].off) ++j;
            int idx = i - a.s[j].off;
            int K = a.s[j].K, N = a.s[j].N;
            int n = idx / K, k = idx - n * K;
            a.s[j].wt[idx] = f2bf(a.s[j].w[(size_t)k * N + n]);
        }
        return;
    }
    b -= a.tBlocks;
    if (b < a.zBlocks) {
        int i = b * 256 + tid;
        if (i < a.zTotal) a.zb[i] = 0.f;
        return;
    }
    b -= a.zBlocks;
    // CSR build: 4 graphs per block
    __shared__ int cnt[4][32], fill[4][32], rs[4][33];
    int gl = tid >> 6, e = tid & 63;
    int g = b * 4 + gl;
    if (e < 32) { cnt[gl][e] = 0; fill[gl][e] = 0; }
    __syncthreads();
    int s = a.src[g * EPG + e] - g * NPG;
    int d = a.dst[g * EPG + e] - g * NPG;
    atomicAdd(&cnt[gl][d], 1);
    __syncthreads();
    if (e == 0) {
        int acc = 0;
        for (int i = 0; i < 32; ++i) { rs[gl][i] = acc; acc += cnt[gl][i]; }
        rs[gl][32] = acc;
    }
    __syncthreads();
    int pos = rs[gl][d] + atomicAdd(&fill[gl][d], 1);
    a.col_idx[g * EPG + pos] = s;
    if (e < 33) a.row_start[g * 33 + e] = rs[gl][e];
}

// ---------------------------------------------------------------------------
// NNODE GEMM, K = N = 128, tile 128x128. COALESCED A staging (contiguous
// float4 per thread) -> transform -> bf16 LDS (pad 8 -> 2-way conflicts only).
// W fragments read straight from global (L2-resident, no LDS). ~40 KB LDS ->
// 4 blocks/CU. Optional skip-C, column stats, per-graph max-pool. In-place
// safe (block reads only its 128 rows before writing them).
// ---------------------------------------------------------------------------
__launch_bounds__(256)
__global__ void gemm_nn(const float* __restrict__ A, const unsigned short* __restrict__ Wt,
                        const float* __restrict__ bias, float* __restrict__ C,
                        const float* __restrict__ in_stats, float inv_sM, int in_mode,
                        float* __restrict__ out_stats, int stats_mode, int out_act,
                        float* __restrict__ pool_out)
{
    __shared__ __align__(16) unsigned short A_l[128 * 136];
    __shared__ float pm[128], pv[128];
    __shared__ float red[4][2][128];

    int tid = threadIdx.x, wave = tid >> 6, lane = tid & 63;
    int quad = lane >> 4, l16 = lane & 15;
    int m0 = blockIdx.x * 128;

    if (in_mode) {
        if (tid < 128) {
            float s = in_stats[tid], ss = in_stats[128 + tid];
            float mn = s * inv_sM;
            float vr = ss * inv_sM - mn * mn;
            pm[tid] = mn; pv[tid] = rsqrtf(vr + BN_EPS);
        }
        __syncthreads();
    }

    // ---- coalesced A stage: 128 rows x 32 float4, 16 per thread ----
    #pragma unroll
    for (int it = 0; it < 16; ++it) {
        int i = it * 256 + tid;
        float4 f = *(const float4*)&A[(size_t)m0 * 128 + (size_t)i * 4];
        int c = (i & 31) * 4;
        if (in_mode) {
            f.x = apply_in(f.x, in_mode, pm[c],     pv[c]);
            f.y = apply_in(f.y, in_mode, pm[c + 1], pv[c + 1]);
            f.z = apply_in(f.z, in_mode, pm[c + 2], pv[c + 2]);
            f.w = apply_in(f.w, in_mode, pm[c + 3], pv[c + 3]);
        }
        int row = i >> 5;
        *(us4*)&A_l[row * 136 + c] = (us4){ f2bf(f.x), f2bf(f.y), f2bf(f.z), f2bf(f.w) };
    }
    __syncthreads();

    f32x4 acc[2][8];
    #pragma unroll
    for (int i = 0; i < 2; ++i)
        #pragma unroll
        for (int j = 0; j < 8; ++j)
            acc[i][j] = (f32x4){0.f, 0.f, 0.f, 0.f};

    #pragma unroll
    for (int ks = 0; ks < 4; ++ks) {
        bf16x8 a0 = *(const bf16x8*)(const void*)&A_l[(wave * 32 + l16) * 136 + ks * 32 + quad * 8];
        bf16x8 a1 = *(const bf16x8*)(const void*)&A_l[(wave * 32 + 16 + l16) * 136 + ks * 32 + quad * 8];
        #pragma unroll
        for (int nt = 0; nt < 8; ++nt) {
            bf16x8 b = *(const bf16x8*)(const void*)&Wt[(size_t)(nt * 16 + l16) * 128 + ks * 32 + quad * 8];
            acc[0][nt] = __builtin_amdgcn_mfma_f32_16x16x32_bf16(a0, b, acc[0][nt], 0, 0, 0);
            acc[1][nt] = __builtin_amdgcn_mfma_f32_16x16x32_bf16(a1, b, acc[1][nt], 0, 0, 0);
        }
    }

    // ---- epilogue ----
    float ls[8], lq[8];
    #pragma unroll
    for (int nt = 0; nt < 8; ++nt) { ls[nt] = 0.f; lq[nt] = 0.f; }

    #pragma unroll
    for (int nt = 0; nt < 8; ++nt) {
        int col = nt * 16 + l16;
        float bv = bias[col];
        float mx = -INFINITY;
        #pragma unroll
        for (int mt = 0; mt < 2; ++mt) {
            int rbase = m0 + wave * 32 + mt * 16 + quad * 4;
            #pragma unroll
            for (int r = 0; r < 4; ++r) {
                float u = acc[mt][nt][r] + bv;
                if (C) {
                    float wv = out_act ? fmaxf(u, 0.f) : u;
                    C[(size_t)(rbase + r) * 128 + col] = wv;
                }
                float ru = fmaxf(u, 0.f);
                if (stats_mode) {
                    float s = (stats_mode == 2) ? ru : u;
                    ls[nt] += s; lq[nt] += s * s;
                }
                if (pool_out) mx = fmaxf(mx, ru);
            }
        }
        if (pool_out) {
            mx = fmaxf(mx, __shfl_xor(mx, 16));
            mx = fmaxf(mx, __shfl_xor(mx, 32));
            if (quad == 0) {
                int graph = (m0 + wave * 32) >> 5;
                pool_out[(size_t)graph * 128 + col] = mx;
            }
        }
    }

    if (stats_mode) {
        #pragma unroll
        for (int nt = 0; nt < 8; ++nt) {
            float s = ls[nt], q = lq[nt];
            s += __shfl_xor(s, 16); q += __shfl_xor(q, 16);
            s += __shfl_xor(s, 32); q += __shfl_xor(q, 32);
            if (quad == 0) { red[wave][0][nt * 16 + l16] = s; red[wave][1][nt * 16 + l16] = q; }
        }
        __syncthreads();
        if (tid < 128) {
            float s = red[0][0][tid] + red[1][0][tid] + red[2][0][tid] + red[3][0][tid];
            float q = red[0][1][tid] + red[1][1][tid] + red[2][1][tid] + red[3][1][tid];
            unsafeAtomicAdd(&out_stats[tid], s);
            unsafeAtomicAdd(&out_stats[128 + tid], q);
        }
    }
}

// ---------------------------------------------------------------------------
// Register-A MFMA GEMM for the 8192-row layers. Tile MT x NT, K <= KSTEPS*32.
// In-place safe.
// ---------------------------------------------------------------------------
template<int MT, int KSTEPS, int NT>
__launch_bounds__(256)
__global__ void gemm_rA(const float* __restrict__ A, const float* __restrict__ A2,
                        int lda, int K, int stats_K, int ksplit,
                        const unsigned short* __restrict__ Wt,
                        const float* __restrict__ bias, float* __restrict__ C,
                        const float* __restrict__ in_stats, float inv_sM, int in_mode,
                        float* __restrict__ out_stats, int stats_mode, int out_act,
                        float* __restrict__ pool_out)
{
    constexpr int LSTRW = KSTEPS * 32 + 8;
    constexpr int NSUB = NT / 16;
    constexpr int MF = MT / 64;          // A-frags per wave
    __shared__ unsigned short Ws_l[NT * LSTRW];
    __shared__ float pm[KSTEPS * 32], pv[KSTEPS * 32];
    __shared__ float red[4][2][NT];

    int tid  = threadIdx.x;
    int wave = tid >> 6;
    int lane = tid & 63;
    int quad = lane >> 4;
    int l16  = lane & 15;
    int m0   = blockIdx.x * MT;

    const bool kvec = ((K & 3) == 0);

    for (int i = tid; i < NT * (KSTEPS * 8); i += 256) {
        int n = i / (KSTEPS * 8), g4 = i % (KSTEPS * 8);
        int k = g4 * 4;
        us4 w = (us4){0, 0, 0, 0};
        if (k < K) {
            const unsigned short* wp = Wt + (size_t)n * K + k;
            if (kvec) w = *(const us4*)wp;
            else {
                w.x = wp[0];
                if (k + 1 < K) w.y = wp[1];
                if (k + 2 < K) w.z = wp[2];
                if (k + 3 < K) w.w = wp[3];
            }
        }
        *(us4*)&Ws_l[n * LSTRW + k] = w;
    }
    if (in_mode) {
        for (int k = tid; k < KSTEPS * 32; k += 256) {
            float mn = 0.f, iv = 1.f;
            if (k < stats_K) {
                float s = in_stats[k], ss = in_stats[stats_K + k];
                mn = s * inv_sM;
                float vr = ss * inv_sM - mn * mn;
                iv = rsqrtf(vr + BN_EPS);
            }
            pm[k] = mn; pv[k] = iv;
        }
    }
    __syncthreads();

    bf16x8 afrag[MF][KSTEPS];
    #pragma unroll
    for (int mt = 0; mt < MF; ++mt) {
        int row = m0 + wave * (16 * MF) + mt * 16 + l16;
        const float* ap = A + (size_t)row * lda;
        #pragma unroll
        for (int ks = 0; ks < KSTEPS; ++ks) {
            int kb = ks * 32 + quad * 8;
            float v[8];
            if (kvec) {
                #pragma unroll
                for (int h = 0; h < 2; ++h) {
                    int k = kb + h * 4;
                    const float* p = (k >= ksplit) ? &A2[(size_t)row * 128 + (k - 128)]
                                                   : &ap[k];
                    float4 f = *(const float4*)p;
                    v[h * 4 + 0] = f.x; v[h * 4 + 1] = f.y;
                    v[h * 4 + 2] = f.z; v[h * 4 + 3] = f.w;
                }
            } else {
                #pragma unroll
                for (int j = 0; j < 8; ++j) {
                    int k = kb + j;
                    v[j] = (k < K) ? ap[k] : 0.f;
                }
            }
            if (in_mode) {
                #pragma unroll
                for (int j = 0; j < 8; ++j)
                    v[j] = apply_in(v[j], in_mode, pm[kb + j], pv[kb + j]);
            }
            union { bf16x8 b; unsigned short u[8]; } fr;
            #pragma unroll
            for (int j = 0; j < 8; ++j) fr.u[j] = f2bf(v[j]);
            afrag[mt][ks] = fr.b;
        }
    }

    f32x4 acc[MF][NSUB];
    #pragma unroll
    for (int i = 0; i < MF; ++i)
        #pragma unroll
        for (int j = 0; j < NSUB; ++j)
            acc[i][j] = (f32x4){0.f, 0.f, 0.f, 0.f};

    #pragma unroll
    for (int ks = 0; ks < KSTEPS; ++ks) {
        #pragma unroll
        for (int nt = 0; nt < NSUB; ++nt) {
            bf16x8 b = *(const bf16x8*)(const void*)&Ws_l[(nt * 16 + l16) * LSTRW + ks * 32 + quad * 8];
            #pragma unroll
            for (int mt = 0; mt < MF; ++mt)
                acc[mt][nt] = __builtin_amdgcn_mfma_f32_16x16x32_bf16(afrag[mt][ks], b, acc[mt][nt], 0, 0, 0);
        }
    }

    float ls[NSUB], lq[NSUB];
    #pragma unroll
    for (int nt = 0; nt < NSUB; ++nt) { ls[nt] = 0.f; lq[nt] = 0.f; }

    #pragma unroll
    for (int nt = 0; nt < NSUB; ++nt) {
        int col = nt * 16 + l16;
        float bv = bias[col];
        float mx = -INFINITY;
        #pragma unroll
        for (int mt = 0; mt < MF; ++mt) {
            int rbase = m0 + wave * (16 * MF) + mt * 16 + quad * 4;
            #pragma unroll
            for (int r = 0; r < 4; ++r) {
                float u = acc[mt][nt][r] + bv;
                if (C) {
                    float wv = out_act ? fmaxf(u, 0.f) : u;
                    C[(size_t)(rbase + r) * NT + col] = wv;
                }
                float ru = fmaxf(u, 0.f);
                if (stats_mode) {
                    float s = (stats_mode == 2) ? ru : u;
                    ls[nt] += s; lq[nt] += s * s;
                }
                if (MF == 2 && pool_out) mx = fmaxf(mx, ru);
            }
        }
        if (MF == 2 && pool_out) {
            mx = fmaxf(mx, __shfl_xor(mx, 16));
            mx = fmaxf(mx, __shfl_xor(mx, 32));
            if (quad == 0) {
                int graph = (m0 + wave * 32) >> 5;
                pool_out[(size_t)graph * NT + col] = mx;
            }
        }
    }

    if (stats_mode) {
        #pragma unroll
        for (int nt = 0; nt < NSUB; ++nt) {
            float s = ls[nt], q = lq[nt];
            s += __shfl_xor(s, 16); q += __shfl_xor(q, 16);
            s += __shfl_xor(s, 32); q += __shfl_xor(q, 32);
            if (quad == 0) { red[wave][0][nt * 16 + l16] = s; red[wave][1][nt * 16 + l16] = q; }
        }
        __syncthreads();
        if (tid < NT) {
            float s = red[0][0][tid] + red[1][0][tid] + red[2][0][tid] + red[3][0][tid];
            float q = red[0][1][tid] + red[1][1][tid] + red[2][1][tid] + red[3][1][tid];
            unsafeAtomicAdd(&out_stats[tid], s);
            unsafeAtomicAdd(&out_stats[NT + tid], q);
        }
    }
}

// ---------------------------------------------------------------------------
// Fused GIN-2: block = 128 rows = 4 whole graphs. Per 64-col chunk: stage
// h = bn(relu(u2)) in fp32 LDS (coalesced loads), GATHER-aggregate via CSR,
// quantize frags, MFMA with W fragments straight from global (L2-resident).
// ~41 KB LDS -> 4 blocks/CU. K = N = 128. In-place safe.
// ---------------------------------------------------------------------------
__launch_bounds__(256)
__global__ void gemm_g21(const float* __restrict__ A,
                         const unsigned short* __restrict__ Wt,
                         const float* __restrict__ bias, float* __restrict__ C,
                         const int* __restrict__ row_start, const int* __restrict__ col_idx,
                         const float* __restrict__ in_stats, float inv_sM,
                         float* __restrict__ out_stats)
{
    __shared__ __align__(16) float xl[128 * 68];   // 34816 B (64 cols + 4 pad)
    __shared__ float pm[128], pv[128];
    __shared__ int rs[132], ci[256];
    __shared__ float red[4][2][128];

    int tid  = threadIdx.x;
    int wave = tid >> 6;
    int lane = tid & 63;
    int quad = lane >> 4;
    int l16  = lane & 15;
    int m0   = blockIdx.x * 128;
    int g0   = m0 >> 5;                // first of 4 graphs

    if (tid < 128) {
        float s = in_stats[tid], ss = in_stats[128 + tid];
        float mn = s * inv_sM;
        float vr = ss * inv_sM - mn * mn;
        pm[tid] = mn;
        pv[tid] = rsqrtf(vr + BN_EPS);
    }
    if (tid < 132) {
        int gl = tid / 33, idx = tid - gl * 33;
        rs[tid] = row_start[(g0 + gl) * 33 + idx];
    }
    {
        int gl = tid >> 6, e = tid & 63;
        ci[tid] = col_idx[(g0 + gl) * EPG + e] + gl * 32;   // block-local row
    }
    __syncthreads();

    f32x4 acc[2][8];
    #pragma unroll
    for (int i = 0; i < 2; ++i)
        #pragma unroll
        for (int j = 0; j < 8; ++j)
            acc[i][j] = (f32x4){0.f, 0.f, 0.f, 0.f};

    for (int ch = 0; ch < 2; ++ch) {
        // stage transformed 64-col chunk (fp32); 128 rows x 16 float4
        for (int i = tid; i < 128 * 16; i += 256) {
            int row = i >> 4, f4 = (i & 15) * 4;
            int k = ch * 64 + f4;
            float4 f = *(const float4*)&A[(size_t)(m0 + row) * 128 + k];
            float4 t;
            t.x = (fmaxf(f.x, 0.f) - pm[k])     * pv[k];
            t.y = (fmaxf(f.y, 0.f) - pm[k + 1]) * pv[k + 1];
            t.z = (fmaxf(f.z, 0.f) - pm[k + 2]) * pv[k + 2];
            t.w = (fmaxf(f.w, 0.f) - pm[k + 3]) * pv[k + 3];
            *(float4*)&xl[row * 68 + f4] = t;
        }
        __syncthreads();

        #pragma unroll
        for (int ks2 = 0; ks2 < 2; ++ks2) {
            int kb = ks2 * 32 + quad * 8;     // offset within chunk [0,64)
            int kg = ch * 64 + kb;
            bf16x8 af[2];
            #pragma unroll
            for (int mt = 0; mt < 2; ++mt) {
                int rowl = wave * 32 + mt * 16 + l16;   // block-local row
                int gl = rowl >> 5, nloc = rowl & 31;
                int e0 = rs[gl * 33 + nloc], e1 = rs[gl * 33 + nloc + 1];
                float v[8];
                #pragma unroll
                for (int j = 0; j < 8; ++j) v[j] = xl[rowl * 68 + kb + j];
                for (int e = e0; e < e1; ++e) {
                    int sr = ci[(gl << 6) + e];
                    #pragma unroll
                    for (int j = 0; j < 8; ++j) v[j] += xl[sr * 68 + kb + j];
                }
                union { bf16x8 b; unsigned short u[8]; } fr;
                #pragma unroll
                for (int j = 0; j < 8; ++j) fr.u[j] = f2bf(v[j]);
                af[mt] = fr.b;
            }
            #pragma unroll
            for (int nt = 0; nt < 8; ++nt) {
                bf16x8 b = *(const bf16x8*)(const void*)&Wt[(size_t)(nt * 16 + l16) * 128 + kg];
                acc[0][nt] = __builtin_amdgcn_mfma_f32_16x16x32_bf16(af[0], b, acc[0][nt], 0, 0, 0);
                acc[1][nt] = __builtin_amdgcn_mfma_f32_16x16x32_bf16(af[1], b, acc[1][nt], 0, 0, 0);
            }
        }
        __syncthreads();   // protect xl before restage
    }

    // epilogue: write u3, stats of u
    float ls[8], lq[8];
    #pragma unroll
    for (int nt = 0; nt < 8; ++nt) { ls[nt] = 0.f; lq[nt] = 0.f; }
    #pragma unroll
    for (int nt = 0; nt < 8; ++nt) {
        int col = nt * 16 + l16;
        float bv = bias[col];
        #pragma unroll
        for (int mt = 0; mt < 2; ++mt) {
            int rbase = m0 + wave * 32 + mt * 16 + quad * 4;
            #pragma unroll
            for (int r = 0; r < 4; ++r) {
                float u = acc[mt][nt][r] + bv;
                C[(size_t)(rbase + r) * 128 + col] = u;
                ls[nt] += u; lq[nt] += u * u;
            }
        }
    }
    #pragma unroll
    for (int nt = 0; nt < 8; ++nt) {
        float s = ls[nt], q = lq[nt];
        s += __shfl_xor(s, 16); q += __shfl_xor(q, 16);
        s += __shfl_xor(s, 32); q += __shfl_xor(q, 32);
        if (quad == 0) { red[wave][0][nt * 16 + l16] = s; red[wave][1][nt * 16 + l16] = q; }
    }
    __syncthreads();
    if (tid < 128) {
        float s = red[0][0][tid] + red[1][0][tid] + red[2][0][tid] + red[3][0][tid];
        float q = red[0][1][tid] + red[1][1][tid] + red[2][1][tid] + red[3][1][tid];
        unsafeAtomicAdd(&out_stats[tid], s);
        unsafeAtomicAdd(&out_stats[128 + tid], q);
    }
}

// ---------------------------------------------------------------------------
// Cell-branch GEMM (large K): tile 64 x NT, 4 waves x 16 rows, K-chunk 64.
// ---------------------------------------------------------------------------
template<int NT>
__launch_bounds__(256)
__global__ void gemm_cell(const float* __restrict__ A, const unsigned short* __restrict__ Wt,
                          const float* __restrict__ bias, float* __restrict__ C,
                          int M, int K, int N,
                          const float* __restrict__ in_stats, float inv_sM, int in_mode,
                          float* __restrict__ out_stats)
{
    constexpr int NSUB = NT / 16;
    __shared__ unsigned short As_l[64 * 72];
    __shared__ unsigned short Ws_l[NT * 72];
    __shared__ float pm[916], pv[916];
    __shared__ float red[4][2][NT];

    int tid = threadIdx.x;
    int wave = tid >> 6;
    int lane = tid & 63;
    int quad = lane >> 4;
    int l16 = lane & 15;
    int m0 = blockIdx.x * 64, n0 = blockIdx.y * NT;

    if (in_mode) {
        for (int k = tid; k < K; k += 256) {
            float s = in_stats[k], ss = in_stats[K + k];
            float mn = s * inv_sM;
            float vr = ss * inv_sM - mn * mn;
            pm[k] = mn; pv[k] = rsqrtf(vr + BN_EPS);
        }
        __syncthreads();
    }

    f32x4 acc[NSUB];
    #pragma unroll
    for (int j = 0; j < NSUB; ++j) acc[j] = (f32x4){0.f, 0.f, 0.f, 0.f};

    for (int k0 = 0; k0 < K; k0 += 64) {
        for (int i = tid; i < 64 * 16; i += 256) {
            int row = i >> 4, f4 = i & 15;
            int k = k0 + f4 * 4;
            us4 w4 = (us4){0, 0, 0, 0};
            if (k < K) {
                float4 f = *(const float4*)&A[(size_t)(m0 + row) * K + k];
                if (in_mode) {
                    f.x = apply_in(f.x, in_mode, pm[k], pv[k]);
                    f.y = apply_in(f.y, in_mode, pm[k + 1], pv[k + 1]);
                    f.z = apply_in(f.z, in_mode, pm[k + 2], pv[k + 2]);
                    f.w = apply_in(f.w, in_mode, pm[k + 3], pv[k + 3]);
                }
                w4 = (us4){ f2bf(f.x), f2bf(f.y), f2bf(f.z), f2bf(f.w) };
            }
            *(us4*)&As_l[row * 72 + f4 * 4] = w4;
        }
        for (int i = tid; i < NT * 16; i += 256) {
            int nn = i >> 4, kt = i & 15;
            int k = k0 + kt * 4;
            int gn = n0 + nn;
            us4 w4 = (us4){0, 0, 0, 0};
            if (gn < N && k < K) w4 = *(const us4*)&Wt[(size_t)gn * K + k];
            *(us4*)&Ws_l[nn * 72 + kt * 4] = w4;
        }
        __syncthreads();
        int rowb = wave * 16;
        #pragma unroll
        for (int ks = 0; ks < 2; ++ks) {
            bf16x8 a = *(const bf16x8*)(const void*)&As_l[(rowb + l16) * 72 + ks * 32 + quad * 8];
            #pragma unroll
            for (int nt = 0; nt < NSUB; ++nt) {
                bf16x8 b = *(const bf16x8*)(const void*)&Ws_l[(nt * 16 + l16) * 72 + ks * 32 + quad * 8];
                acc[nt] = __builtin_amdgcn_mfma_f32_16x16x32_bf16(a, b, acc[nt], 0, 0, 0);
            }
        }
        __syncthreads();
    }

    float ls[NSUB], lq[NSUB];
    #pragma unroll
    for (int nt = 0; nt < NSUB; ++nt) { ls[nt] = 0.f; lq[nt] = 0.f; }

    #pragma unroll
    for (int nt = 0; nt < NSUB; ++nt) {
        int col = n0 + nt * 16 + l16;
        if (col < N) {
            float bv = bias[col];
            int rbase = m0 + wave * 16 + quad * 4;
            #pragma unroll
            for (int r = 0; r < 4; ++r) {
                float u = acc[nt][r] + bv;
                C[(size_t)(rbase + r) * N + col] = u;
                ls[nt] += u; lq[nt] += u * u;
            }
        }
    }

    #pragma unroll
    for (int nt = 0; nt < NSUB; ++nt) {
        float s = ls[nt], q = lq[nt];
        s += __shfl_xor(s, 16); q += __shfl_xor(q, 16);
        s += __shfl_xor(s, 32); q += __shfl_xor(q, 32);
        if (quad == 0) { red[wave][0][nt * 16 + l16] = s; red[wave][1][nt * 16 + l16] = q; }
    }
    __syncthreads();
    if (tid < NT) {
        int col = n0 + tid;
        if (col < N) {
            float s = red[0][0][tid] + red[1][0][tid] + red[2][0][tid] + red[3][0][tid];
            float q = red[0][1][tid] + red[1][1][tid] + red[2][1][tid] + red[3][1][tid];
            unsafeAtomicAdd(&out_stats[col], s);
            unsafeAtomicAdd(&out_stats[N + col], q);
        }
    }
}

// ---------------------------------------------------------------------------
// GIN conv-1 input aggregation (F=9): out = x + segment_sum(x[src], dst)
// ---------------------------------------------------------------------------
__global__ void gin_agg9(const float* __restrict__ x, const int* __restrict__ src,
                         const int* __restrict__ dst, float* __restrict__ out)
{
    const int F = 9;
    __shared__ float xl[32 * F];
    __shared__ float acb[32 * F];
    __shared__ int es[EPG], ed[EPG];
    int g = blockIdx.x;
    int tid = threadIdx.x;
    size_t base = (size_t)g * 32 * F;
    for (int i = tid; i < 32 * F; i += blockDim.x) {
        float v = x[base + i];
        xl[i] = v;
        acb[i] = v;
    }
    if (tid < EPG) {
        es[tid] = src[g * EPG + tid] - g * NPG;
        ed[tid] = dst[g * EPG + tid] - g * NPG;
    }
    __syncthreads();
    if (tid < 64) {
        int e = tid;
        for (int c = 0; c < F; ++c)
            atomicAdd(&acb[ed[e] * F + c], xl[es[e] * F + c]);
    }
    __syncthreads();
    for (int i = tid; i < 32 * F; i += blockDim.x)
        out[base + i] = acb[i];
}

// ---------------------------------------------------------------------------
// Final: y[i] = elu(bn(u[i,:])) . w + b   (K = 64)
// ---------------------------------------------------------------------------
__global__ void final_dot(const float* __restrict__ u, const float* __restrict__ w,
                          const float* __restrict__ b, float* __restrict__ y,
                          const float* __restrict__ stats, float inv_sM)
{
    __shared__ float pmv[64], piv[64], sw[64];
    int tid = threadIdx.x;
    if (tid < 64) {
        float s = stats[tid], ss = stats[64 + tid];
        float mn = s * inv_sM;
        float vr = ss * inv_sM - mn * mn;
        pmv[tid] = mn;
        piv[tid] = rsqrtf(vr + BN_EPS);
        sw[tid] = w[tid];
    }
    __syncthreads();
    int i = blockIdx.x * blockDim.x + tid;
    if (i >= BGRAPH) return;
    float acc = 0.f;
    #pragma unroll
    for (int k = 0; k < 64; ++k) {
        float v = (u[(size_t)i * 64 + k] - pmv[k]) * piv[k];
        v = (v > 0.f) ? v : expm1f(v);
        acc += v * sw[k];
    }
    y[i] = acc + b[0];
}

// ---------------------------------------------------------------------------
// Host driver. 13 launches, ~149 MB workspace.
// ---------------------------------------------------------------------------
extern "C" void kernel_launch(void* const* d_in, const int* in_sizes, int n_in,
                              void* d_out, int out_size, void* d_ws, size_t ws_size,
                              hipStream_t stream)
{
    const float* cell   = (const float*)d_in[0];
    const float* drug_x = (const float*)d_in[1];
    const int*   eidx   = (const int*)d_in[2];
    const float* ce1w = (const float*)d_in[4];  const float* ce1b = (const float*)d_in[5];
    const float* ce2w = (const float*)d_in[6];  const float* ce2b = (const float*)d_in[7];
    const float* ce3w = (const float*)d_in[8];  const float* ce3b = (const float*)d_in[9];
    const float* g11w = (const float*)d_in[10]; const float* g11b = (const float*)d_in[11];
    const float* g12w = (const float*)d_in[12]; const float* g12b = (const float*)d_in[13];
    const float* g21w = (const float*)d_in[14]; const float* g21b = (const float*)d_in[15];
    const float* g22w = (const float*)d_in[16]; const float* g22b = (const float*)d_in[17];
    const float* d1w  = (const float*)d_in[18]; const float* d1b  = (const float*)d_in[19];
    const float* d2w  = (const float*)d_in[20]; const float* d2b  = (const float*)d_in[21];
    const float* f1w  = (const float*)d_in[22]; const float* f1b  = (const float*)d_in[23];
    const float* f2w  = (const float*)d_in[24]; const float* f2b  = (const float*)d_in[25];
    const float* f3w  = (const float*)d_in[26]; const float* f3b  = (const float*)d_in[27];

    const int* src = eidx;
    const int* dst = eidx + NEDGE;
    float* out = (float*)d_out;

    const float INV_N = 1.f / (float)NNODE;
    const float INV_B = 1.f / (float)BGRAPH;
    const int KBIG = 1 << 30;

    // ---- workspace layout ----
    float* ws   = (float*)d_ws;
    float* big  = ws;                                   // NNODE*128 floats
    float* aux  = ws + (size_t)NNODE * 128;             // NNODE*9 floats
    float* sb   = aux + (size_t)NNODE * 9;              // 10*1032 stats floats
    unsigned short* wtb = (unsigned short*)(sb + 10 * 1032);
    auto ST = [&](int i) { return sb + (size_t)i * 1032; };
    float* st_u1    = ST(0);
    float* st_u2rel = ST(1);
    float* st_u3    = ST(2);
    float* st_u4rel = ST(3);
    float* st_c1    = ST(4);
    float* st_c2    = ST(5);
    float* st_c3    = ST(6);
    float* st_d1    = ST(7);
    float* st_f1    = ST(8);
    float* st_f2    = ST(9);

    struct WDef { const float* w; int K; int N; };
    WDef wd[11] = {
        {ce1w, CELLD, 516}, {ce2w, 516, 256}, {ce3w, 256, 128},
        {g11w, 9, 128}, {g12w, 128, 128}, {g21w, 128, 128}, {g22w, 128, 128},
        {d1w, 128, 128}, {d2w, 128, 128}, {f1w, 256, 128}, {f2w, 128, 64}
    };
    SetupArgs sa;
    int off = 0;
    unsigned short* wt[11];
    for (int i = 0; i < 11; ++i) {
        wt[i] = wtb + off;
        sa.s[i] = TSeg{ wd[i].w, wt[i], wd[i].K, wd[i].N, off };
        off += wd[i].K * wd[i].N;
    }
    sa.tTotal = off;
    sa.tBlocks = (off + 255) / 256;
    sa.zb = sb; sa.zTotal = 10 * 1032; sa.zBlocks = (10 * 1032 + 255) / 256;
    sa.src = src; sa.dst = dst;

    int csr_off = (off + 7) & ~7;     // 16-B align
    int* row_start = (int*)(wtb + csr_off);
    int* col_idx   = row_start + (size_t)BGRAPH * 33;
    sa.row_start = row_start; sa.col_idx = col_idx;

    // small buffers inside `big` (used only after GIN branch is done with it)
    float* c1    = big;
    float* c2    = c1 + (size_t)BGRAPH * 516;
    float* c3u   = c2 + (size_t)BGRAPH * 256;
    float* dbuf  = c3u + (size_t)BGRAPH * 128;
    float* d2buf = dbuf + (size_t)BGRAPH * 128;
    float* f1o   = d2buf + (size_t)BGRAPH * 128;
    float* f2o   = f1o + (size_t)BGRAPH * 128;
    float* pbuf  = aux;   // reused once g11 consumed aux

    setup_all<<<sa.tBlocks + sa.zBlocks + BGRAPH / 4, 256, 0, stream>>>(sa);

    // ================= GIN branch (in-place in `big`) ========================
    gin_agg9<<<BGRAPH, 128, 0, stream>>>(drug_x, src, dst, aux);
    gemm_rA<128, 1, 128><<<NNODE / 128, 256, 0, stream>>>(
        aux, nullptr, 9, 9, 9, KBIG, wt[3], g11b, big,
        nullptr, 0.f, 0, st_u1, 1, 0, nullptr);
    // g12: relu(bn(u1)) @ W, stats of relu(u2)  [coalesced-A kernel]
    gemm_nn<<<NNODE / 128, 256, 0, stream>>>(
        big, wt[4], g12b, big, st_u1, INV_N, 1, st_u2rel, 2, 0, nullptr);
    // g21 with fused gather-aggregation (h = bn(relu(u2)); u3 = (h+agg)@W)
    gemm_g21<<<NNODE / 128, 256, 0, stream>>>(
        big, wt[5], g21b, big, row_start, col_idx, st_u2rel, INV_N, st_u3);
    // g22: relu(bn(u3)) @ W; no C write; stats of relu(u4); pool max(relu(u4))
    gemm_nn<<<NNODE / 128, 256, 0, stream>>>(
        big, wt[6], g22b, nullptr, st_u3, INV_N, 1, st_u4rel, 2, 0, pbuf);

    // ================= cell branch ===========================================
    gemm_cell<128><<<dim3(BGRAPH / 64, 5), 256, 0, stream>>>(
        cell, wt[0], ce1b, c1, BGRAPH, CELLD, 516, nullptr, 0.f, 0, st_c1);
    gemm_cell<64><<<dim3(BGRAPH / 64, 4), 256, 0, stream>>>(
        c1, wt[1], ce2b, c2, BGRAPH, 516, 256, st_c1, INV_B, 1, st_c2);
    gemm_rA<64, 8, 128><<<BGRAPH / 64, 256, 0, stream>>>(
        c2, nullptr, 256, 256, 256, KBIG, wt[2], ce3b, c3u,
        st_c2, INV_B, 1, st_c3, 1, 0, nullptr);

    // ================= d branch ==============================================
    gemm_rA<64, 4, 128><<<BGRAPH / 64, 256, 0, stream>>>(
        pbuf, nullptr, 128, 128, 128, KBIG, wt[7], d1b, dbuf,
        st_u4rel, INV_N, 3, st_d1, 1, 0, nullptr);
    gemm_rA<64, 4, 128><<<BGRAPH / 64, 256, 0, stream>>>(
        dbuf, nullptr, 128, 128, 128, KBIG, wt[8], d2b, d2buf,
        st_d1, INV_B, 1, nullptr, 0, 1, nullptr);

    // ================= head ==================================================
    gemm_rA<64, 8, 128><<<BGRAPH / 64, 256, 0, stream>>>(
        c3u, d2buf, 128, 256, 128, 128, wt[9], f1b, f1o,
        st_c3, INV_B, 1, st_f1, 1, 0, nullptr);
    gemm_rA<64, 4, 64><<<BGRAPH / 64, 256, 0, stream>>>(
        f1o, nullptr, 128, 128, 128, KBIG, wt[10], f2b, f2o,
        st_f1, INV_B, 2, st_f2, 1, 0, nullptr);
    final_dot<<<BGRAPH / 256, 256, 0, stream>>>(f2o, f3w, f3b, out, st_f2, INV_B);
}

// Round 10
// 776.731 us; speedup vs baseline: 1.5422x; 1.0349x over previous
//
#include <hip/hip_runtime.h>
#include <hip/hip_bf16.h>
#include <math.h>

// Problem constants (from reference)
#define BGRAPH 8192
#define NPG 32
#define EPG 64
#define NNODE (BGRAPH * NPG)   // 262144
#define NEDGE (BGRAPH * EPG)   // 524288
#define CELLD 908
#define BN_EPS 1e-5f

typedef __attribute__((ext_vector_type(8))) short bf16x8;   // 8 bf16 = 4 VGPRs
typedef __attribute__((ext_vector_type(4))) float f32x4;
typedef __attribute__((ext_vector_type(4))) unsigned short us4;

__device__ __forceinline__ unsigned short f2bf(float f)
{
    unsigned int u = __float_as_uint(f);
    u = (u + 0x7FFFu + ((u >> 16) & 1u)) >> 16;   // RNE
    return (unsigned short)u;
}

__device__ __forceinline__ bf16x8 quant8(const float v[8])
{
    union { bf16x8 b; unsigned short u[8]; } fr;
    #pragma unroll
    for (int j = 0; j < 8; ++j) fr.u[j] = f2bf(v[j]);
    return fr.b;
}

// in_mode: 0=raw, 1=relu((x-m)*iv), 2=elu((x-m)*iv), 3=(relu(x)-m)*iv
__device__ __forceinline__ float apply_in(float v, int mode, float mn, float iv)
{
    if (mode == 1)      { v = (v - mn) * iv; v = fmaxf(v, 0.f); }
    else if (mode == 2) { v = (v - mn) * iv; v = (v > 0.f) ? v : expm1f(v); }
    else if (mode == 3) { v = fmaxf(v, 0.f); v = (v - mn) * iv; }
    return v;
}

// ---------------------------------------------------------------------------
// Merged setup: weight transpose+bf16, stats zero, per-graph in-edge CSR.
// ---------------------------------------------------------------------------
struct TSeg { const float* w; unsigned short* wt; int K; int N; int off; };
struct SetupArgs {
    TSeg s[11]; int tTotal; int tBlocks;
    float* zb; int zTotal; int zBlocks;
    const int* src; const int* dst; int* row_start; int* col_idx;
};

__global__ void setup_all(SetupArgs a)
{
    int b = blockIdx.x;
    int tid = threadIdx.x;
    if (b < a.tBlocks) {
        int i = b * 256 + tid;
        if (i < a.tTotal) {
            int j = 0;
            while (j < 10 && i >= a.s[j + 1].off) ++j;
            int idx = i - a.s[j].off;
            int K = a.s[j].K, N = a.s[j].N;
            int n = idx / K, k = idx - n * K;
            a.s[j].wt[idx] = f2bf(a.s[j].w[(size_t)k * N + n]);
        }
        return;
    }
    b -= a.tBlocks;
    if (b < a.zBlocks) {
        int i = b * 256 + tid;
        if (i < a.zTotal) a.zb[i] = 0.f;
        return;
    }
    b -= a.zBlocks;
    // CSR build: 4 graphs per block
    __shared__ int cnt[4][32], fill[4][32], rsl[4][33];
    int gl = tid >> 6, e = tid & 63;
    int g = b * 4 + gl;
    if (e < 32) { cnt[gl][e] = 0; fill[gl][e] = 0; }
    __syncthreads();
    int s = a.src[g * EPG + e] - g * NPG;
    int d = a.dst[g * EPG + e] - g * NPG;
    atomicAdd(&cnt[gl][d], 1);
    __syncthreads();
    if (e == 0) {
        int acc = 0;
        for (int i = 0; i < 32; ++i) { rsl[gl][i] = acc; acc += cnt[gl][i]; }
        rsl[gl][32] = acc;
    }
    __syncthreads();
    int pos = rsl[gl][d] + atomicAdd(&fill[gl][d], 1);
    a.col_idx[g * EPG + pos] = s;
    if (e < 33) a.row_start[g * 33 + e] = rsl[gl][e];
}

// ---------------------------------------------------------------------------
// GIN chain by RECOMPUTE: block = 128 rows = 4 graphs, wave = 1 graph.
// Recomputes from drug_x up to stage DEPTH; emits ONLY that stage's column
// stats (+ pooled max at DEPTH 4). No NNODE-sized global reads/writes.
// Chain: a = x + agg(x); u1 = a@W11+b11 [stats raw @D1]
//        u2 = relu(bn(u1))@W12+b12     [stats relu @D2]
//        h  = bn(relu(u2)); u3 = (h+agg(h))@W21+b21 [stats raw @D3]
//        u4 = relu(bn(u3))@W22+b22     [stats relu + pool @D4]
// LDS ~77 KB -> 2 blocks/CU. h-tile per wave: 32 x 132 fp32.
// ---------------------------------------------------------------------------
#define HST 132   // h row stride (floats): 132*4=528 B, 16B-aligned, bank-shift 4

template<int DEPTH>
__launch_bounds__(256)
__global__ void gin_chain(const float* __restrict__ drug_x,
                          const int* __restrict__ row_start,
                          const int* __restrict__ col_idx,
                          const unsigned short* __restrict__ W11,   // [128][9]
                          const float* __restrict__ b11,
                          const unsigned short* __restrict__ W12, const float* __restrict__ b12,
                          const unsigned short* __restrict__ W21, const float* __restrict__ b21,
                          const unsigned short* __restrict__ W22, const float* __restrict__ b22,
                          const float* __restrict__ st1,   // stats(u1), used D>=2
                          const float* __restrict__ st2,   // stats(relu u2), used D>=3
                          const float* __restrict__ st3,   // stats(u3), used D>=4
                          float invM,
                          float* __restrict__ out_stats,
                          float* __restrict__ pool_out)
{
    __shared__ __align__(16) float h[4 * 32 * HST];     // 67584 B (xw overlays)
    __shared__ __align__(16) unsigned short w11l[128 * 16];  // 4 KB, zero-padded K
    __shared__ int rs[4][33];
    __shared__ int ci[4][64];
    __shared__ float red[4][2][128];

    int tid  = threadIdx.x;
    int wave = tid >> 6;
    int lane = tid & 63;
    int quad = lane >> 4;
    int l16  = lane & 15;
    int g0   = blockIdx.x * 4;
    float* hw = h + wave * (32 * HST);

    // ---- setup: W11 -> LDS (padded), CSR, raw x tile (stride 16, padded) ----
    for (int i = tid; i < 128 * 16; i += 256) {
        int n = i >> 4, k = i & 15;
        w11l[i] = (k < 9) ? W11[n * 9 + k] : (unsigned short)0;
    }
    if (tid < 132) {
        int gl = tid / 33, idx = tid - gl * 33;
        rs[gl][idx] = row_start[(g0 + gl) * 33 + idx];
    }
    {
        int gl = tid >> 6, e = tid & 63;
        ci[gl][e] = col_idx[(g0 + gl) * EPG + e];
    }
    {
        const float* xg = drug_x + (size_t)(g0 + wave) * 32 * 9;
        for (int i = lane; i < 32 * 16; i += 64) {
            int rr = i >> 4, c = i & 15;
            hw[i] = (c < 9) ? xg[rr * 9 + c] : 0.f;   // xw overlays hw
        }
    }
    __syncthreads();

    f32x4 acc[2][8];
    #pragma unroll
    for (int i = 0; i < 2; ++i)
        #pragma unroll
        for (int j = 0; j < 8; ++j)
            acc[i][j] = (f32x4){0.f, 0.f, 0.f, 0.f};

    // ======== stage 1: u1 = (x + agg(x)) @ W11 + b11 (K padded to 32) =======
    {
        bf16x8 af[2];
        #pragma unroll
        for (int mt = 0; mt < 2; ++mt) {
            int rowl = mt * 16 + l16;
            float v[8] = {0, 0, 0, 0, 0, 0, 0, 0};
            if (quad < 2) {
                float4 lo = *(const float4*)&hw[rowl * 16 + quad * 8];
                float4 hi = *(const float4*)&hw[rowl * 16 + quad * 8 + 4];
                v[0] = lo.x; v[1] = lo.y; v[2] = lo.z; v[3] = lo.w;
                v[4] = hi.x; v[5] = hi.y; v[6] = hi.z; v[7] = hi.w;
                int e0 = rs[wave][rowl], e1 = rs[wave][rowl + 1];
                for (int e = e0; e < e1; ++e) {
                    int sr = ci[wave][e];
                    float4 l2 = *(const float4*)&hw[sr * 16 + quad * 8];
                    float4 h2 = *(const float4*)&hw[sr * 16 + quad * 8 + 4];
                    v[0] += l2.x; v[1] += l2.y; v[2] += l2.z; v[3] += l2.w;
                    v[4] += h2.x; v[5] += h2.y; v[6] += h2.z; v[7] += h2.w;
                }
            }
            af[mt] = quant8(v);
        }
        #pragma unroll
        for (int nt = 0; nt < 8; ++nt) {
            bf16x8 b;
            if (quad < 2) b = *(const bf16x8*)(const void*)&w11l[(nt * 16 + l16) * 16 + quad * 8];
            else { float z[8] = {0,0,0,0,0,0,0,0}; b = quant8(z); }
            acc[0][nt] = __builtin_amdgcn_mfma_f32_16x16x32_bf16(af[0], b, acc[0][nt], 0, 0, 0);
            acc[1][nt] = __builtin_amdgcn_mfma_f32_16x16x32_bf16(af[1], b, acc[1][nt], 0, 0, 0);
        }
        #pragma unroll
        for (int nt = 0; nt < 8; ++nt) {
            float bv = b11[nt * 16 + l16];
            #pragma unroll
            for (int mt = 0; mt < 2; ++mt)
                #pragma unroll
                for (int r = 0; r < 4; ++r) acc[mt][nt][r] += bv;
        }
    }

    // ---- helper lambdas ----
    // transform acc (C-layout) -> h tile; MODE 1: relu(bn(u)); MODE 3: bn(relu(u))
    auto transform_store = [&](const float* st, int mode) {
        #pragma unroll
        for (int nt = 0; nt < 8; ++nt) {
            int col = nt * 16 + l16;
            float s = st[col], ss = st[128 + col];
            float mn = s * invM;
            float iv = rsqrtf(ss * invM - mn * mn + BN_EPS);
            #pragma unroll
            for (int mt = 0; mt < 2; ++mt)
                #pragma unroll
                for (int r = 0; r < 4; ++r) {
                    float u = acc[mt][nt][r];
                    float t = (mode == 1) ? fmaxf((u - mn) * iv, 0.f)
                                          : (fmaxf(u, 0.f) - mn) * iv;
                    hw[(mt * 16 + quad * 4 + r) * HST + col] = t;
                }
        }
    };
    // GEMM from h tile (K=128), B from global; optional CSR gather on A rows
    auto gemm_h = [&](const unsigned short* Wt, const float* bias, bool gather) {
        #pragma unroll
        for (int i = 0; i < 2; ++i)
            #pragma unroll
            for (int j = 0; j < 8; ++j)
                acc[i][j] = (f32x4){0.f, 0.f, 0.f, 0.f};
        #pragma unroll
        for (int ks = 0; ks < 4; ++ks) {
            bf16x8 af[2];
            #pragma unroll
            for (int mt = 0; mt < 2; ++mt) {
                int rowl = mt * 16 + l16;
                int kb = ks * 32 + quad * 8;
                float4 lo = *(const float4*)&hw[rowl * HST + kb];
                float4 hi = *(const float4*)&hw[rowl * HST + kb + 4];
                float v[8] = {lo.x, lo.y, lo.z, lo.w, hi.x, hi.y, hi.z, hi.w};
                if (gather) {
                    int e0 = rs[wave][rowl], e1 = rs[wave][rowl + 1];
                    for (int e = e0; e < e1; ++e) {
                        int sr = ci[wave][e];
                        float4 l2 = *(const float4*)&hw[sr * HST + kb];
                        float4 h2 = *(const float4*)&hw[sr * HST + kb + 4];
                        v[0] += l2.x; v[1] += l2.y; v[2] += l2.z; v[3] += l2.w;
                        v[4] += h2.x; v[5] += h2.y; v[6] += h2.z; v[7] += h2.w;
                    }
                }
                af[mt] = quant8(v);
            }
            #pragma unroll
            for (int nt = 0; nt < 8; ++nt) {
                bf16x8 b = *(const bf16x8*)(const void*)&Wt[(size_t)(nt * 16 + l16) * 128 + ks * 32 + quad * 8];
                acc[0][nt] = __builtin_amdgcn_mfma_f32_16x16x32_bf16(af[0], b, acc[0][nt], 0, 0, 0);
                acc[1][nt] = __builtin_amdgcn_mfma_f32_16x16x32_bf16(af[1], b, acc[1][nt], 0, 0, 0);
            }
        }
        #pragma unroll
        for (int nt = 0; nt < 8; ++nt) {
            float bv = bias[nt * 16 + l16];
            #pragma unroll
            for (int mt = 0; mt < 2; ++mt)
                #pragma unroll
                for (int r = 0; r < 4; ++r) acc[mt][nt][r] += bv;
        }
    };

    if constexpr (DEPTH >= 2) {
        transform_store(st1, 1);     // relu(bn(u1))
        __syncthreads();
        gemm_h(W12, b12, false);     // u2
    }
    if constexpr (DEPTH >= 3) {
        __syncthreads();             // h free before rewrite
        transform_store(st2, 3);     // h = bn(relu(u2))
        __syncthreads();
        gemm_h(W21, b21, true);      // u3 = (h + agg(h)) @ W21
    }
    if constexpr (DEPTH >= 4) {
        __syncthreads();
        transform_store(st3, 1);     // relu(bn(u3))
        __syncthreads();
        gemm_h(W22, b22, false);     // u4
    }

    // ======== stats (+pool) epilogue for stage DEPTH ========
    constexpr bool RELU_STATS = (DEPTH == 2 || DEPTH == 4);
    float ls[8], lq[8];
    #pragma unroll
    for (int nt = 0; nt < 8; ++nt) { ls[nt] = 0.f; lq[nt] = 0.f; }
    #pragma unroll
    for (int nt = 0; nt < 8; ++nt) {
        int col = nt * 16 + l16;
        float mx = -INFINITY;
        #pragma unroll
        for (int mt = 0; mt < 2; ++mt)
            #pragma unroll
            for (int r = 0; r < 4; ++r) {
                float u = acc[mt][nt][r];
                float ru = fmaxf(u, 0.f);
                float s = RELU_STATS ? ru : u;
                ls[nt] += s; lq[nt] += s * s;
                if (DEPTH == 4) mx = fmaxf(mx, ru);
            }
        if (DEPTH == 4) {
            mx = fmaxf(mx, __shfl_xor(mx, 16));
            mx = fmaxf(mx, __shfl_xor(mx, 32));
            if (quad == 0) pool_out[(size_t)(g0 + wave) * 128 + col] = mx;
        }
    }
    #pragma unroll
    for (int nt = 0; nt < 8; ++nt) {
        float s = ls[nt], q = lq[nt];
        s += __shfl_xor(s, 16); q += __shfl_xor(q, 16);
        s += __shfl_xor(s, 32); q += __shfl_xor(q, 32);
        if (quad == 0) { red[wave][0][nt * 16 + l16] = s; red[wave][1][nt * 16 + l16] = q; }
    }
    __syncthreads();
    if (tid < 128) {
        float s = red[0][0][tid] + red[1][0][tid] + red[2][0][tid] + red[3][0][tid];
        float q = red[0][1][tid] + red[1][1][tid] + red[2][1][tid] + red[3][1][tid];
        unsafeAtomicAdd(&out_stats[tid], s);
        unsafeAtomicAdd(&out_stats[128 + tid], q);
    }
}

// ---------------------------------------------------------------------------
// Register-A MFMA GEMM for the 8192-row layers. Tile 64 x NT, K <= KSTEPS*32.
// In-place safe.
// ---------------------------------------------------------------------------
template<int KSTEPS, int NT>
__launch_bounds__(256)
__global__ void gemm_rA(const float* __restrict__ A, const float* __restrict__ A2,
                        int lda, int K, int stats_K, int ksplit,
                        const unsigned short* __restrict__ Wt,
                        const float* __restrict__ bias, float* __restrict__ C,
                        const float* __restrict__ in_stats, float inv_sM, int in_mode,
                        float* __restrict__ out_stats, int stats_mode, int out_act)
{
    constexpr int LSTRW = KSTEPS * 32 + 8;
    constexpr int NSUB = NT / 16;
    __shared__ unsigned short Ws_l[NT * LSTRW];
    __shared__ float pm[KSTEPS * 32], pv[KSTEPS * 32];
    __shared__ float red[4][2][NT];

    int tid  = threadIdx.x;
    int wave = tid >> 6;
    int lane = tid & 63;
    int quad = lane >> 4;
    int l16  = lane & 15;
    int m0   = blockIdx.x * 64;

    const bool kvec = ((K & 3) == 0);

    for (int i = tid; i < NT * (KSTEPS * 8); i += 256) {
        int n = i / (KSTEPS * 8), g4 = i % (KSTEPS * 8);
        int k = g4 * 4;
        us4 w = (us4){0, 0, 0, 0};
        if (k < K) {
            const unsigned short* wp = Wt + (size_t)n * K + k;
            if (kvec) w = *(const us4*)wp;
            else {
                w.x = wp[0];
                if (k + 1 < K) w.y = wp[1];
                if (k + 2 < K) w.z = wp[2];
                if (k + 3 < K) w.w = wp[3];
            }
        }
        *(us4*)&Ws_l[n * LSTRW + k] = w;
    }
    if (in_mode) {
        for (int k = tid; k < KSTEPS * 32; k += 256) {
            float mn = 0.f, iv = 1.f;
            if (k < stats_K) {
                float s = in_stats[k], ss = in_stats[stats_K + k];
                mn = s * inv_sM;
                float vr = ss * inv_sM - mn * mn;
                iv = rsqrtf(vr + BN_EPS);
            }
            pm[k] = mn; pv[k] = iv;
        }
    }
    __syncthreads();

    bf16x8 afrag[KSTEPS];
    {
        int row = m0 + wave * 16 + l16;
        const float* ap = A + (size_t)row * lda;
        #pragma unroll
        for (int ks = 0; ks < KSTEPS; ++ks) {
            int kb = ks * 32 + quad * 8;
            float v[8];
            if (kvec) {
                #pragma unroll
                for (int hh = 0; hh < 2; ++hh) {
                    int k = kb + hh * 4;
                    const float* p = (k >= ksplit) ? &A2[(size_t)row * 128 + (k - 128)]
                                                   : &ap[k];
                    float4 f = *(const float4*)p;
                    v[hh * 4 + 0] = f.x; v[hh * 4 + 1] = f.y;
                    v[hh * 4 + 2] = f.z; v[hh * 4 + 3] = f.w;
                }
            } else {
                #pragma unroll
                for (int j = 0; j < 8; ++j) {
                    int k = kb + j;
                    v[j] = (k < K) ? ap[k] : 0.f;
                }
            }
            if (in_mode) {
                #pragma unroll
                for (int j = 0; j < 8; ++j)
                    v[j] = apply_in(v[j], in_mode, pm[kb + j], pv[kb + j]);
            }
            afrag[ks] = quant8(v);
        }
    }

    f32x4 acc[NSUB];
    #pragma unroll
    for (int j = 0; j < NSUB; ++j) acc[j] = (f32x4){0.f, 0.f, 0.f, 0.f};

    #pragma unroll
    for (int ks = 0; ks < KSTEPS; ++ks) {
        #pragma unroll
        for (int nt = 0; nt < NSUB; ++nt) {
            bf16x8 b = *(const bf16x8*)(const void*)&Ws_l[(nt * 16 + l16) * LSTRW + ks * 32 + quad * 8];
            acc[nt] = __builtin_amdgcn_mfma_f32_16x16x32_bf16(afrag[ks], b, acc[nt], 0, 0, 0);
        }
    }

    float ls[NSUB], lq[NSUB];
    #pragma unroll
    for (int nt = 0; nt < NSUB; ++nt) { ls[nt] = 0.f; lq[nt] = 0.f; }

    #pragma unroll
    for (int nt = 0; nt < NSUB; ++nt) {
        int col = nt * 16 + l16;
        float bv = bias[col];
        int rbase = m0 + wave * 16 + quad * 4;
        #pragma unroll
        for (int r = 0; r < 4; ++r) {
            float u = acc[nt][r] + bv;
            if (C) {
                float wv = out_act ? fmaxf(u, 0.f) : u;
                C[(size_t)(rbase + r) * NT + col] = wv;
            }
            if (stats_mode) {
                float s = (stats_mode == 2) ? fmaxf(u, 0.f) : u;
                ls[nt] += s; lq[nt] += s * s;
            }
        }
    }

    if (stats_mode) {
        #pragma unroll
        for (int nt = 0; nt < NSUB; ++nt) {
            float s = ls[nt], q = lq[nt];
            s += __shfl_xor(s, 16); q += __shfl_xor(q, 16);
            s += __shfl_xor(s, 32); q += __shfl_xor(q, 32);
            if (quad == 0) { red[wave][0][nt * 16 + l16] = s; red[wave][1][nt * 16 + l16] = q; }
        }
        __syncthreads();
        if (tid < NT) {
            float s = red[0][0][tid] + red[1][0][tid] + red[2][0][tid] + red[3][0][tid];
            float q = red[0][1][tid] + red[1][1][tid] + red[2][1][tid] + red[3][1][tid];
            unsafeAtomicAdd(&out_stats[tid], s);
            unsafeAtomicAdd(&out_stats[NT + tid], q);
        }
    }
}

// ---------------------------------------------------------------------------
// Cell-branch GEMM (large K): tile 64 x NT, 4 waves x 16 rows, K-chunk 64.
// ---------------------------------------------------------------------------
template<int NT>
__launch_bounds__(256)
__global__ void gemm_cell(const float* __restrict__ A, const unsigned short* __restrict__ Wt,
                          const float* __restrict__ bias, float* __restrict__ C,
                          int M, int K, int N,
                          const float* __restrict__ in_stats, float inv_sM, int in_mode,
                          float* __restrict__ out_stats)
{
    constexpr int NSUB = NT / 16;
    __shared__ unsigned short As_l[64 * 72];
    __shared__ unsigned short Ws_l[NT * 72];
    __shared__ float pm[916], pv[916];
    __shared__ float red[4][2][NT];

    int tid = threadIdx.x;
    int wave = tid >> 6;
    int lane = tid & 63;
    int quad = lane >> 4;
    int l16 = lane & 15;
    int m0 = blockIdx.x * 64, n0 = blockIdx.y * NT;

    if (in_mode) {
        for (int k = tid; k < K; k += 256) {
            float s = in_stats[k], ss = in_stats[K + k];
            float mn = s * inv_sM;
            float vr = ss * inv_sM - mn * mn;
            pm[k] = mn; pv[k] = rsqrtf(vr + BN_EPS);
        }
        __syncthreads();
    }

    f32x4 acc[NSUB];
    #pragma unroll
    for (int j = 0; j < NSUB; ++j) acc[j] = (f32x4){0.f, 0.f, 0.f, 0.f};

    for (int k0 = 0; k0 < K; k0 += 64) {
        for (int i = tid; i < 64 * 16; i += 256) {
            int row = i >> 4, f4 = i & 15;
            int k = k0 + f4 * 4;
            us4 w4 = (us4){0, 0, 0, 0};
            if (k < K) {
                float4 f = *(const float4*)&A[(size_t)(m0 + row) * K + k];
                if (in_mode) {
                    f.x = apply_in(f.x, in_mode, pm[k], pv[k]);
                    f.y = apply_in(f.y, in_mode, pm[k + 1], pv[k + 1]);
                    f.z = apply_in(f.z, in_mode, pm[k + 2], pv[k + 2]);
                    f.w = apply_in(f.w, in_mode, pm[k + 3], pv[k + 3]);
                }
                w4 = (us4){ f2bf(f.x), f2bf(f.y), f2bf(f.z), f2bf(f.w) };
            }
            *(us4*)&As_l[row * 72 + f4 * 4] = w4;
        }
        for (int i = tid; i < NT * 16; i += 256) {
            int nn = i >> 4, kt = i & 15;
            int k = k0 + kt * 4;
            int gn = n0 + nn;
            us4 w4 = (us4){0, 0, 0, 0};
            if (gn < N && k < K) w4 = *(const us4*)&Wt[(size_t)gn * K + k];
            *(us4*)&Ws_l[nn * 72 + kt * 4] = w4;
        }
        __syncthreads();
        int rowb = wave * 16;
        #pragma unroll
        for (int ks = 0; ks < 2; ++ks) {
            bf16x8 a = *(const bf16x8*)(const void*)&As_l[(rowb + l16) * 72 + ks * 32 + quad * 8];
            #pragma unroll
            for (int nt = 0; nt < NSUB; ++nt) {
                bf16x8 b = *(const bf16x8*)(const void*)&Ws_l[(nt * 16 + l16) * 72 + ks * 32 + quad * 8];
                acc[nt] = __builtin_amdgcn_mfma_f32_16x16x32_bf16(a, b, acc[nt], 0, 0, 0);
            }
        }
        __syncthreads();
    }

    float ls[NSUB], lq[NSUB];
    #pragma unroll
    for (int nt = 0; nt < NSUB; ++nt) { ls[nt] = 0.f; lq[nt] = 0.f; }

    #pragma unroll
    for (int nt = 0; nt < NSUB; ++nt) {
        int col = n0 + nt * 16 + l16;
        if (col < N) {
            float bv = bias[col];
            int rbase = m0 + wave * 16 + quad * 4;
            #pragma unroll
            for (int r = 0; r < 4; ++r) {
                float u = acc[nt][r] + bv;
                C[(size_t)(rbase + r) * N + col] = u;
                ls[nt] += u; lq[nt] += u * u;
            }
        }
    }

    #pragma unroll
    for (int nt = 0; nt < NSUB; ++nt) {
        float s = ls[nt], q = lq[nt];
        s += __shfl_xor(s, 16); q += __shfl_xor(q, 16);
        s += __shfl_xor(s, 32); q += __shfl_xor(q, 32);
        if (quad == 0) { red[wave][0][nt * 16 + l16] = s; red[wave][1][nt * 16 + l16] = q; }
    }
    __syncthreads();
    if (tid < NT) {
        int col = n0 + tid;
        if (col < N) {
            float s = red[0][0][tid] + red[1][0][tid] + red[2][0][tid] + red[3][0][tid];
            float q = red[0][1][tid] + red[1][1][tid] + red[2][1][tid] + red[3][1][tid];
            unsafeAtomicAdd(&out_stats[col], s);
            unsafeAtomicAdd(&out_stats[N + col], q);
        }
    }
}

// ---------------------------------------------------------------------------
// Final: y[i] = elu(bn(u[i,:])) . w + b   (K = 64)
// ---------------------------------------------------------------------------
__global__ void final_dot(const float* __restrict__ u, const float* __restrict__ w,
                          const float* __restrict__ b, float* __restrict__ y,
                          const float* __restrict__ stats, float inv_sM)
{
    __shared__ float pmv[64], piv[64], sw[64];
    int tid = threadIdx.x;
    if (tid < 64) {
        float s = stats[tid], ss = stats[64 + tid];
        float mn = s * inv_sM;
        float vr = ss * inv_sM - mn * mn;
        pmv[tid] = mn;
        piv[tid] = rsqrtf(vr + BN_EPS);
        sw[tid] = w[tid];
    }
    __syncthreads();
    int i = blockIdx.x * blockDim.x + tid;
    if (i >= BGRAPH) return;
    float acc = 0.f;
    #pragma unroll
    for (int k = 0; k < 64; ++k) {
        float v = (u[(size_t)i * 64 + k] - pmv[k]) * piv[k];
        v = (v > 0.f) ? v : expm1f(v);
        acc += v * sw[k];
    }
    y[i] = acc + b[0];
}

// ---------------------------------------------------------------------------
// Host driver. 12 launches.
// ---------------------------------------------------------------------------
extern "C" void kernel_launch(void* const* d_in, const int* in_sizes, int n_in,
                              void* d_out, int out_size, void* d_ws, size_t ws_size,
                              hipStream_t stream)
{
    const float* cell   = (const float*)d_in[0];
    const float* drug_x = (const float*)d_in[1];
    const int*   eidx   = (const int*)d_in[2];
    const float* ce1w = (const float*)d_in[4];  const float* ce1b = (const float*)d_in[5];
    const float* ce2w = (const float*)d_in[6];  const float* ce2b = (const float*)d_in[7];
    const float* ce3w = (const float*)d_in[8];  const float* ce3b = (const float*)d_in[9];
    const float* g11w = (const float*)d_in[10]; const float* g11b = (const float*)d_in[11];
    const float* g12w = (const float*)d_in[12]; const float* g12b = (const float*)d_in[13];
    const float* g21w = (const float*)d_in[14]; const float* g21b = (const float*)d_in[15];
    const float* g22w = (const float*)d_in[16]; const float* g22b = (const float*)d_in[17];
    const float* d1w  = (const float*)d_in[18]; const float* d1b  = (const float*)d_in[19];
    const float* d2w  = (const float*)d_in[20]; const float* d2b  = (const float*)d_in[21];
    const float* f1w  = (const float*)d_in[22]; const float* f1b  = (const float*)d_in[23];
    const float* f2w  = (const float*)d_in[24]; const float* f2b  = (const float*)d_in[25];
    const float* f3w  = (const float*)d_in[26]; const float* f3b  = (const float*)d_in[27];

    const int* src = eidx;
    const int* dst = eidx + NEDGE;
    float* out = (float*)d_out;

    const float INV_N = 1.f / (float)NNODE;
    const float INV_B = 1.f / (float)BGRAPH;
    const int KBIG = 1 << 30;

    // ---- workspace layout ----
    float* ws   = (float*)d_ws;
    float* big  = ws;                                   // small buffers live here
    float* aux  = ws + (size_t)NNODE * 128;
    float* sb   = aux + (size_t)NNODE * 9;              // 10*1032 stats floats
    unsigned short* wtb = (unsigned short*)(sb + 10 * 1032);
    auto ST = [&](int i) { return sb + (size_t)i * 1032; };
    float* st_u1    = ST(0);
    float* st_u2rel = ST(1);
    float* st_u3    = ST(2);
    float* st_u4rel = ST(3);
    float* st_c1    = ST(4);
    float* st_c2    = ST(5);
    float* st_c3    = ST(6);
    float* st_d1    = ST(7);
    float* st_f1    = ST(8);
    float* st_f2    = ST(9);

    struct WDef { const float* w; int K; int N; };
    WDef wd[11] = {
        {ce1w, CELLD, 516}, {ce2w, 516, 256}, {ce3w, 256, 128},
        {g11w, 9, 128}, {g12w, 128, 128}, {g21w, 128, 128}, {g22w, 128, 128},
        {d1w, 128, 128}, {d2w, 128, 128}, {f1w, 256, 128}, {f2w, 128, 64}
    };
    SetupArgs sa;
    int off = 0;
    unsigned short* wt[11];
    for (int i = 0; i < 11; ++i) {
        wt[i] = wtb + off;
        sa.s[i] = TSeg{ wd[i].w, wt[i], wd[i].K, wd[i].N, off };
        off += wd[i].K * wd[i].N;
    }
    sa.tTotal = off;
    sa.tBlocks = (off + 255) / 256;
    sa.zb = sb; sa.zTotal = 10 * 1032; sa.zBlocks = (10 * 1032 + 255) / 256;
    sa.src = src; sa.dst = dst;

    int csr_off = (off + 7) & ~7;
    int* row_start = (int*)(wtb + csr_off);
    int* col_idx   = row_start + (size_t)BGRAPH * 33;
    sa.row_start = row_start; sa.col_idx = col_idx;

    float* c1    = big;
    float* c2    = c1 + (size_t)BGRAPH * 516;
    float* c3u   = c2 + (size_t)BGRAPH * 256;
    float* dbuf  = c3u + (size_t)BGRAPH * 128;
    float* d2buf = dbuf + (size_t)BGRAPH * 128;
    float* f1o   = d2buf + (size_t)BGRAPH * 128;
    float* f2o   = f1o + (size_t)BGRAPH * 128;
    float* pbuf  = aux;

    setup_all<<<sa.tBlocks + sa.zBlocks + BGRAPH / 4, 256, 0, stream>>>(sa);

    // ================= GIN branch: recompute chain, no NNODE I/O ============
    gin_chain<1><<<BGRAPH / 4, 256, 0, stream>>>(
        drug_x, row_start, col_idx, wt[3], g11b, wt[4], g12b, wt[5], g21b, wt[6], g22b,
        st_u1, st_u2rel, st_u3, INV_N, st_u1, nullptr);
    gin_chain<2><<<BGRAPH / 4, 256, 0, stream>>>(
        drug_x, row_start, col_idx, wt[3], g11b, wt[4], g12b, wt[5], g21b, wt[6], g22b,
        st_u1, st_u2rel, st_u3, INV_N, st_u2rel, nullptr);
    gin_chain<3><<<BGRAPH / 4, 256, 0, stream>>>(
        drug_x, row_start, col_idx, wt[3], g11b, wt[4], g12b, wt[5], g21b, wt[6], g22b,
        st_u1, st_u2rel, st_u3, INV_N, st_u3, nullptr);
    gin_chain<4><<<BGRAPH / 4, 256, 0, stream>>>(
        drug_x, row_start, col_idx, wt[3], g11b, wt[4], g12b, wt[5], g21b, wt[6], g22b,
        st_u1, st_u2rel, st_u3, INV_N, st_u4rel, pbuf);

    // ================= cell branch ===========================================
    gemm_cell<128><<<dim3(BGRAPH / 64, 5), 256, 0, stream>>>(
        cell, wt[0], ce1b, c1, BGRAPH, CELLD, 516, nullptr, 0.f, 0, st_c1);
    gemm_cell<64><<<dim3(BGRAPH / 64, 4), 256, 0, stream>>>(
        c1, wt[1], ce2b, c2, BGRAPH, 516, 256, st_c1, INV_B, 1, st_c2);
    gemm_rA<8, 128><<<BGRAPH / 64, 256, 0, stream>>>(
        c2, nullptr, 256, 256, 256, KBIG, wt[2], ce3b, c3u,
        st_c2, INV_B, 1, st_c3, 1, 0);

    // ================= d branch ==============================================
    gemm_rA<4, 128><<<BGRAPH / 64, 256, 0, stream>>>(
        pbuf, nullptr, 128, 128, 128, KBIG, wt[7], d1b, dbuf,
        st_u4rel, INV_N, 3, st_d1, 1, 0);
    gemm_rA<4, 128><<<BGRAPH / 64, 256, 0, stream>>>(
        dbuf, nullptr, 128, 128, 128, KBIG, wt[8], d2b, d2buf,
        st_d1, INV_B, 1, nullptr, 0, 1);

    // ================= head ==================================================
    gemm_rA<8, 128><<<BGRAPH / 64, 256, 0, stream>>>(
        c3u, d2buf, 128, 256, 128, 128, wt[9], f1b, f1o,
        st_c3, INV_B, 1, st_f1, 1, 0);
    gemm_rA<4, 64><<<BGRAPH / 64, 256, 0, stream>>>(
        f1o, nullptr, 128, 128, 128, KBIG, wt[10], f2b, f2o,
        st_f1, INV_B, 2, st_f2, 1, 0);
    final_dot<<<BGRAPH / 256, 256, 0, stream>>>(f2o, f3w, f3b, out, st_f2, INV_B);
}